// Round 2
// baseline (208.855 us; speedup 1.0000x reference)
//
#include <hip/hip_runtime.h>
#include <math.h>

#define DM   1024
#define TTOK 2048
#define NTOK 4096   // B*T

typedef __bf16 bf16x8 __attribute__((ext_vector_type(8)));
typedef __bf16 bf16x4 __attribute__((ext_vector_type(4)));
typedef float  f32x4  __attribute__((ext_vector_type(4)));
typedef float  f32x16 __attribute__((ext_vector_type(16)));

// Q pre-scale: sm_scale (1/8) * log2(e)  -> allows p = exp2(s)
#define QSCALE 0.18033688011112042f

#if defined(__has_builtin)
#if __has_builtin(__builtin_amdgcn_exp2f)
#define EXP2F(x) __builtin_amdgcn_exp2f(x)
#endif
#endif
#ifndef EXP2F
#define EXP2F(x) exp2f(x)
#endif

#define GLDS16(g, l) __builtin_amdgcn_global_load_lds( \
    (__attribute__((address_space(1))) void*)(g),      \
    (__attribute__((address_space(3))) void*)(l), 16, 0, 0)

// ---------------- fp32 -> bf16 convert: x + 4 weights in ONE launch ----------------
__global__ __launch_bounds__(256)
void cvt_all(const float* __restrict__ x,  const float* __restrict__ Wq,
             const float* __restrict__ Wk, const float* __restrict__ Wv,
             const float* __restrict__ Wo, __bf16* __restrict__ dst) {
    size_t g = ((size_t)blockIdx.x * 256 + threadIdx.x) * 8;
    const float* s;
    size_t off;
    const size_t NX = (size_t)NTOK * DM;   // 4M
    if (g < NX) { s = x; off = g; }
    else {
        size_t gg = g - NX;
        int w = (int)(gg >> 20);           // 1M-element segments
        off = gg & ((1u << 20) - 1);
        s = (w == 0) ? Wq : (w == 1) ? Wk : (w == 2) ? Wv : Wo;
    }
    float4 a = *(const float4*)(s + off);
    float4 b = *(const float4*)(s + off + 4);
    bf16x8 v;
    v[0] = (__bf16)a.x; v[1] = (__bf16)a.y; v[2] = (__bf16)a.z; v[3] = (__bf16)a.w;
    v[4] = (__bf16)b.x; v[5] = (__bf16)b.y; v[6] = (__bf16)b.z; v[7] = (__bf16)b.w;
    *(bf16x8*)(dst + g) = v;
}

// =====================================================================
// bf16 MFMA GEMM: C[m,n] = sum_k A[m,k] * B[n,k], 128x128 tile, BK=32.
// Double-buffered LDS staging; next-tile global_load_lds issued BEFORE
// current-tile compute; ONE barrier per K-step.
// LDS tiles are stored in FRAGMENT ORDER (rule #21: global_load_lds
// writes linearly, so the per-lane GLOBAL SOURCE is permuted instead):
//   16B-chunk index c = (row>>4)*64 + kquad*16 + (row&15)
// which makes every frag ds_read_b128 lane-consecutive (0 conflicts;
// the old row-major [row][32] layout was an 8-way conflict).
// MODE 0 (QKV, grid z) with LDS-transpose epilogue (packed 16B stores):
//   z=0: A=Wq, B=x (m=hd, n=token) -> Q[b,h,t,d] * QSCALE
//   z=1: A=Wk, B=x                  -> K[b,h,t,d]
//   z=2: A=x,  B=Wv (m=token, n=hd) -> Vt[b,h,d,t]
// MODE 1 (out-proj): A=Zm (m=token), B=Wo (n=Dout) -> out[t][D] fp32.
//   Grid is XCD-swizzled so XCD c owns m-rows [512c,512c+512): per-XCD
//   working set = 1MB Zm + 2MB Wo = 3MB <= 4MB L2 (1 block/CU kernel is
//   latency-exposed; L2-hits cut the exposed latency ~3x).
// =====================================================================
#define LSTR 136   // LDS transpose stride (16B-aligned rows, conflict-free)
#define DBUF 8192  // elems per staging buffer (As 4096 + Bs 4096)

template<int MODE>
__global__ __launch_bounds__(256)
void gemm_bf16(const __bf16* __restrict__ X,
               const __bf16* __restrict__ W0, const __bf16* __restrict__ W1,
               const __bf16* __restrict__ W2,
               __bf16* __restrict__ Oq, __bf16* __restrict__ Ok,
               __bf16* __restrict__ Ovt, float* __restrict__ Of)
{
    const int z = (MODE == 0) ? blockIdx.z : 3;
    const __bf16 *A, *B;
    int m0, n0;
    if (MODE == 0 && z < 2) {        // W·x^T : m=hd(1024), n=token(4096)
        A = z ? W1 : W0; B = X;
        m0 = blockIdx.y * 128; n0 = blockIdx.x * 128;
    } else if (MODE == 0) {          // x·Wv^T : m=token, n=hd
        A = X; B = W2;
        m0 = blockIdx.x * 128; n0 = blockIdx.y * 128;
    } else {                         // Zm·Wo^T : m=token(4096), n=Dout(1024)
        A = X; B = W0;
        int f = blockIdx.x + 8 * blockIdx.y;   // 0..255
        int c = f & 7, i = f >> 3;             // XCD c = f%8 (round-robin)
        m0 = (4 * c + (i & 3)) * 128;          // XCD c -> m-rows [512c,512c+512)
        n0 = (i >> 2) * 128;
    }

    // union: double-buffer staging (2 x (As 4K + Bs 4K) = 16K elems)
    //        / 128x136 transpose buffer (17408 elems)
    __shared__ __attribute__((aligned(16))) __bf16 smem[128 * LSTR];

    const int tid  = threadIdx.x;
    const int lane = tid & 63;
    const int wave = tid >> 6;
    const int wm = wave & 1, wn = wave >> 1;
    const int col = lane & 15, quad = lane >> 4;

    // staging source permutation: thread tid stages global (row arow,
    // k-chunk akc) so that LDS chunk `tid` holds frag-order data.
    const int arow = ((tid >> 6) << 4) + (tid & 15);   // 0..63
    const int akc  = (tid >> 4) & 3;
    const __bf16* Ag = A + (size_t)(m0 + arow) * DM + akc * 8;
    const __bf16* Bg = B + (size_t)(n0 + arow) * DM + akc * 8;
    __bf16* lA = smem + tid * 8;            // As slot in buffer 0
    __bf16* lB = smem + 4096 + tid * 8;     // Bs slot in buffer 0

    f32x4 acc[4][4];
#pragma unroll
    for (int i = 0; i < 4; ++i)
#pragma unroll
        for (int j = 0; j < 4; ++j)
#pragma unroll
            for (int r = 0; r < 4; ++r) acc[i][j][r] = 0.0f;

    // ---- prologue: stage K-step 0 into buffer 0 ----
    GLDS16(Ag,                   lA);
    GLDS16(Ag + (size_t)64 * DM, lA + 2048);
    GLDS16(Bg,                   lB);
    GLDS16(Bg + (size_t)64 * DM, lB + 2048);
    __syncthreads();   // vmcnt(0) drained by compiler: buf0 ready

    const int nk = DM / 32;   // 32 K-steps
    for (int t = 0; t < nk; ++t) {
        const int cur = (t & 1) * DBUF;
        const int nxt = DBUF - cur;

        // issue next-tile loads FIRST — latency spans the compute below
        if (t + 1 < nk) {
            const int k1 = (t + 1) * 32;
            GLDS16(Ag + k1,                   lA + nxt);
            GLDS16(Ag + (size_t)64 * DM + k1, lA + nxt + 2048);
            GLDS16(Bg + k1,                   lB + nxt);
            GLDS16(Bg + (size_t)64 * DM + k1, lB + nxt + 2048);
        }

        const __bf16* Asr = smem + cur;
        const __bf16* Bsr = smem + cur + 4096;
        bf16x8 af[4], bfr[4];
#pragma unroll
        for (int i = 0; i < 4; ++i)
            af[i] = *(const bf16x8*)&Asr[((wm * 4 + i) * 64 + lane) * 8];
#pragma unroll
        for (int j = 0; j < 4; ++j)
            bfr[j] = *(const bf16x8*)&Bsr[((wn * 4 + j) * 64 + lane) * 8];
#pragma unroll
        for (int i = 0; i < 4; ++i)
#pragma unroll
            for (int j = 0; j < 4; ++j)
                acc[i][j] = __builtin_amdgcn_mfma_f32_16x16x32_bf16(af[i], bfr[j], acc[i][j], 0, 0, 0);

        // one barrier per K-step: drains next-tile vmcnt AFTER compute,
        // and guarantees all reads of buffer `cur` completed before it is
        // overwritten in iteration t+2.
        __syncthreads();
    }

    if (MODE == 1) {
        // scalar n-fastest fp32 stores: 16 lanes = 64B contiguous
#pragma unroll
        for (int i = 0; i < 4; ++i)
#pragma unroll
            for (int j = 0; j < 4; ++j) {
                const int mb = m0 + wm * 64 + i * 16 + quad * 4;
                const int n  = n0 + wn * 64 + j * 16 + col;
#pragma unroll
                for (int r = 0; r < 4; ++r)
                    Of[(size_t)(mb + r) * DM + n] = acc[i][j][r];
            }
        return;
    }

    // ---- MODE 0: LDS transpose -> packed global stores ----
    // (loop-trailing barrier already guarantees staging reads are done)
    const float sc = (z == 0) ? QSCALE : 1.0f;
#pragma unroll
    for (int i = 0; i < 4; ++i)
#pragma unroll
        for (int j = 0; j < 4; ++j) {
            const int ml = wm * 64 + i * 16 + quad * 4;
            const int nl = wn * 64 + j * 16 + col;
            bf16x4 pk;
#pragma unroll
            for (int r = 0; r < 4; ++r) pk[r] = (__bf16)(acc[i][j][r] * sc);
            *(bf16x4*)&smem[nl * LSTR + ml] = pk;   // Ls[n][m]
        }
    __syncthreads();

    // 128 rows x 16 chunks of 8 elems = 2048 chunks; 8 iterations x 256 thr
#pragma unroll
    for (int it = 0; it < 8; ++it) {
        int c   = tid + 256 * it;
        int row = c >> 4;          // n_local
        int ch  = (c & 15) * 8;    // m_local base
        bf16x8 v = *(const bf16x8*)&smem[row * LSTR + ch];
        if (z < 2) {
            // row = token, ch = hd: d-contiguous segments of Q/K[b,h,t,d]
            int t  = n0 + row;
            int b  = t >> 11; t &= 2047;
            int hd = m0 + ch;
            int h  = hd >> 6, d = hd & 63;
            *(bf16x8*)&((z ? Ok : Oq)[(((size_t)(b * 16 + h)) * TTOK + t) * 64 + d]) = v;
        } else {
            // row = hd, ch = token: t-contiguous segments of Vt[b,h,d,t]
            int hd = n0 + row;
            int h  = hd >> 6, d = hd & 63;
            int t  = m0 + ch;
            int b  = t >> 11; t &= 2047;
            *(bf16x8*)&Ovt[(((size_t)(b * 16 + h)) * 64 + d) * TTOK + t] = v;
        }
    }
}

// =====================================================================
// MFMA flash attention v6: 32x32x16 frags, FRAGMENT-ORDERED LDS.
// 256 threads (4 waves), 128 q/block, 32 q/wave.
// All hot ds_read_b128 are lane-consecutive (0 bank conflicts); staging
// writes are 2-way (free). Layouts (elems):
//   Kf/Vf[((st*2+h)*64 + row)*8 + e]   row=key|d, k-elem = st*16+h*8+e
//   QPf: per-wave 2048-elem region; Q frags then P tile, same frag order
// S^T = K·Q^T (M=keys, N=q); p = exp2 (log2e folded into Q);
// l = mfma(ones, P, l); O^T = V^T·P; exclusive-mod epilogue.
// =====================================================================
__global__ __launch_bounds__(256)
void attn_mfma(const __bf16* __restrict__ Qg, const __bf16* __restrict__ Kg,
               const __bf16* __restrict__ Vtg, __bf16* __restrict__ Zm)
{
    const int bh = blockIdx.y;
    const int q0 = blockIdx.x * 128;
    const size_t base = (size_t)bh * TTOK * 64;

    __shared__ __attribute__((aligned(16))) __bf16 Kf[4096];   // 8 KB
    __shared__ __attribute__((aligned(16))) __bf16 Vf[4096];   // 8 KB
    __shared__ __attribute__((aligned(16))) __bf16 QPf[8192];  // 16 KB

    const int tid  = threadIdx.x;
    const int lane = tid & 63, wave = tid >> 6;   // wave 0..3
    const int c32  = lane & 31, h32 = lane >> 5;

    // ---- stage Q (pre-scaled by QSCALE in GEMM) in frag order ----
#pragma unroll
    for (int it = 0; it < 2; ++it) {
        int idx = tid + 256 * it;              // 0..511
        int r = idx >> 2, c = idx & 3;
        const __bf16* src = Qg + base + (size_t)(q0 + r) * 64 + c * 16;
        __bf16* qr = QPf + (r >> 5) * 2048;    // wave region
        *(bf16x8*)&qr[(c * 64 + (r & 31)) * 8]      = *(const bf16x8*)(src);
        *(bf16x8*)&qr[(c * 64 + 32 + (r & 31)) * 8] = *(const bf16x8*)(src + 8);
    }
    __syncthreads();
    bf16x8 qf[4];
#pragma unroll
    for (int st = 0; st < 4; ++st)
        qf[st] = *(const bf16x8*)&QPf[wave * 2048 + ((st * 2 + h32) * 32 + c32) * 8];
    // wave's region is reused as its P tile below (only rows it read)

    bf16x8 ones;
#pragma unroll
    for (int i = 0; i < 8; ++i) ones[i] = (__bf16)1.0f;

    f32x16 O[2], lacc;
#pragma unroll
    for (int r = 0; r < 16; ++r) { O[0][r] = 0.0f; O[1][r] = 0.0f; lacc[r] = 0.0f; }

    const int rs = tid >> 2, cc = tid & 3;     // staging: row rs, k-chunk cc
    const int soff = cc * 16;

    // prefetch tile 0
    bf16x8 kr0 = *(const bf16x8*)(Kg  + base + (size_t)rs * 64 + soff);
    bf16x8 kr1 = *(const bf16x8*)(Kg  + base + (size_t)rs * 64 + soff + 8);
    bf16x8 vr0 = *(const bf16x8*)(Vtg + base + (size_t)rs * TTOK + soff);
    bf16x8 vr1 = *(const bf16x8*)(Vtg + base + (size_t)rs * TTOK + soff + 8);

    // epilogue V snapshot coords: wave's q-rows live in key-tile kb_tgt
    const int kb_tgt = (q0 >> 6) + (wave >> 1);
    const int qo     = (wave & 1) * 32 + c32;
    const int qsb    = ((qo >> 4) * 2 + ((qo >> 3) & 1)) * 512 + (qo & 7);
    float vq[2][16];

    for (int kb = 0; kb < TTOK / 64; ++kb) {
        __syncthreads();   // prior tile's Kf/Vf frag reads complete
        *(bf16x8*)&Kf[(cc * 128 + rs) * 8]      = kr0;   // (st=cc,h=0)
        *(bf16x8*)&Kf[(cc * 128 + 64 + rs) * 8] = kr1;   // (st=cc,h=1)
        *(bf16x8*)&Vf[(cc * 128 + rs) * 8]      = vr0;
        *(bf16x8*)&Vf[(cc * 128 + 64 + rs) * 8] = vr1;
        __syncthreads();

        // prefetch next tile — latency spans the compute below
        {
            int kbn = (kb + 1) & (TTOK / 64 - 1);
            const __bf16* kp = Kg  + base + (size_t)(kbn * 64 + rs) * 64 + soff;
            const __bf16* vp = Vtg + base + (size_t)rs * TTOK + kbn * 64 + soff;
            kr0 = *(const bf16x8*)(kp); kr1 = *(const bf16x8*)(kp + 8);
            vr0 = *(const bf16x8*)(vp); vr1 = *(const bf16x8*)(vp + 8);
        }

        // ---- S^T = K·Q^T ----
        f32x16 s0, s1;
#pragma unroll
        for (int r = 0; r < 16; ++r) { s0[r] = 0.0f; s1[r] = 0.0f; }
#pragma unroll
        for (int st = 0; st < 4; ++st) {
            bf16x8 a0 = *(const bf16x8*)&Kf[((st * 2 + h32) * 64 + c32) * 8];
            bf16x8 a1 = *(const bf16x8*)&Kf[((st * 2 + h32) * 64 + 32 + c32) * 8];
            s0 = __builtin_amdgcn_mfma_f32_32x32x16_bf16(a0, qf[st], s0, 0, 0, 0);
            s1 = __builtin_amdgcn_mfma_f32_32x32x16_bf16(a1, qf[st], s1, 0, 0, 0);
        }

        // ---- p = exp2(s); write P[q][key] in frag order (8B stores) ----
#pragma unroll
        for (int kb2 = 0; kb2 < 2; ++kb2) {
#pragma unroll
            for (int g = 0; g < 4; ++g) {
                float p0 = EXP2F(kb2 ? s1[4 * g + 0] : s0[4 * g + 0]);
                float p1 = EXP2F(kb2 ? s1[4 * g + 1] : s0[4 * g + 1]);
                float p2 = EXP2F(kb2 ? s1[4 * g + 2] : s0[4 * g + 2]);
                float p3 = EXP2F(kb2 ? s1[4 * g + 3] : s0[4 * g + 3]);
                bf16x4 pk;
                pk[0] = (__bf16)p0; pk[1] = (__bf16)p1;
                pk[2] = (__bf16)p2; pk[3] = (__bf16)p3;
                // keys kb2*32+g*8+h32*4+{0..3} -> st=2kb2+(g>>1), h=g&1
                *(bf16x4*)&QPf[wave * 2048 + ((4 * kb2 + g) * 32 + c32) * 8 + h32 * 4] = pk;
            }
        }

        // ---- O^T += V^T·P ; l += 1·P ----
#pragma unroll
        for (int ks = 0; ks < 4; ++ks) {
            bf16x8 pf = *(const bf16x8*)&QPf[wave * 2048 + ((ks * 2 + h32) * 32 + c32) * 8];
            lacc = __builtin_amdgcn_mfma_f32_32x32x16_bf16(ones, pf, lacc, 0, 0, 0);
            bf16x8 v0 = *(const bf16x8*)&Vf[((ks * 2 + h32) * 64 + c32) * 8];
            bf16x8 v1 = *(const bf16x8*)&Vf[((ks * 2 + h32) * 64 + 32 + c32) * 8];
            O[0] = __builtin_amdgcn_mfma_f32_32x32x16_bf16(v0, pf, O[0], 0, 0, 0);
            O[1] = __builtin_amdgcn_mfma_f32_32x32x16_bf16(v1, pf, O[1], 0, 0, 0);
        }

        // ---- snapshot own-q V column from LDS (wave-uniform branch) ----
        if (kb == kb_tgt) {
#pragma unroll
            for (int db = 0; db < 2; ++db)
#pragma unroll
                for (int rg = 0; rg < 16; ++rg) {
                    int d = db * 32 + (rg & 3) + 8 * (rg >> 2) + 4 * h32;
                    vq[db][rg] = (float)Vf[qsb + d * 8];
                }
        }
    }

    const float inv = 1.0f / lacc[0];

    // ---- epilogue: Y = O/l ; exclusive output mod ; packed bf16 store ----
    const int b = bh >> 4, h = bh & 15;
    const int q = q0 + wave * 32 + c32;
    float y[2][16];
    float yv = 0.f, v2 = 0.f, yy = 0.f;
#pragma unroll
    for (int db = 0; db < 2; ++db)
#pragma unroll
        for (int rg = 0; rg < 16; ++rg) {
            float yval = O[db][rg] * inv;
            float vval = vq[db][rg];
            y[db][rg] = yval;
            yv += yval * vval; v2 += vval * vval; yy += yval * yval;
        }
    yv += __shfl_xor(yv, 32, 64);
    v2 += __shfl_xor(v2, 32, 64);
    yy += __shfl_xor(yy, 32, 64);
    float scl = (v2 > 0.0f) ? yv / fmaxf(v2, 1.1754943508222875e-38f) : 0.0f;
    float zz = 0.f;
    float zvv[2][16];
#pragma unroll
    for (int db = 0; db < 2; ++db)
#pragma unroll
        for (int rg = 0; rg < 16; ++rg) {
            zvv[db][rg] = y[db][rg] - scl * vq[db][rg];
            zz += zvv[db][rg] * zvv[db][rg];
        }
    zz += __shfl_xor(zz, 32, 64);
    float znorm = sqrtf(zz);
    float refn  = fmaxf(sqrtf(yy), sqrtf(v2));
    bool  wipe  = (v2 > 0.0f) && (znorm <= 1.1920928955078125e-07f * 64.0f * refn);
#pragma unroll
    for (int db = 0; db < 2; ++db)
#pragma unroll
        for (int g = 0; g < 4; ++g) {
            bf16x4 pk;
#pragma unroll
            for (int r = 0; r < 4; ++r)
                pk[r] = (__bf16)(wipe ? 0.0f : zvv[db][4 * g + r]);
            int d = db * 32 + 8 * g + 4 * h32;
            *(bf16x4*)&Zm[((size_t)(b * TTOK + q)) * DM + h * 64 + d] = pk;
        }
}

// =====================================================================
extern "C" void kernel_launch(void* const* d_in, const int* in_sizes, int n_in,
                              void* d_out, int out_size, void* d_ws, size_t ws_size,
                              hipStream_t stream) {
    const float* x  = (const float*)d_in[0];
    const float* Wq = (const float*)d_in[1];
    const float* Wk = (const float*)d_in[2];
    const float* Wv = (const float*)d_in[3];
    const float* Wo = (const float*)d_in[4];

    const size_t NX = (size_t)NTOK * DM;   // 4M
    const size_t NW = (size_t)DM * DM;     // 1M
    __bf16* xb  = (__bf16*)d_ws;
    __bf16* wqb = xb  + NX;
    __bf16* wkb = wqb + NW;
    __bf16* wvb = wkb + NW;
    __bf16* wob = wvb + NW;
    __bf16* Qb  = wob + NW;
    __bf16* Kb  = Qb  + NX;
    __bf16* Vtb = Kb  + NX;
    __bf16* Zmb = Vtb + NX;   // total 24M bf16 = 48 MB

    cvt_all<<<(NX + 4 * NW) / 2048, 256, 0, stream>>>(x, Wq, Wk, Wv, Wo, xb);

    // QKV: z0/z1 = Wq,Wk · x^T ; z2 = x · Wv^T  (LDS-transpose epilogues)
    gemm_bf16<0><<<dim3(32, 8, 3), 256, 0, stream>>>(
        xb, wqb, wkb, wvb, Qb, Kb, Vtb, nullptr);

    attn_mfma<<<dim3(TTOK / 128, 32), 256, 0, stream>>>(Qb, Kb, Vtb, Zmb);

    // out = Zm · Wo^T (m=token, n=Dout; XCD-swizzled grid)
    gemm_bf16<1><<<dim3(8, 32), 256, 0, stream>>>(
        Zmb, wob, nullptr, nullptr, nullptr, nullptr, nullptr, (float*)d_out);
}

// Round 3
// 188.086 us; speedup vs baseline: 1.1104x; 1.1104x over previous
//
#include <hip/hip_runtime.h>
#include <math.h>

#define DM   1024
#define TTOK 2048
#define NTOK 4096   // B*T

typedef __bf16 bf16x8 __attribute__((ext_vector_type(8)));
typedef __bf16 bf16x4 __attribute__((ext_vector_type(4)));
typedef float  f32x4  __attribute__((ext_vector_type(4)));
typedef float  f32x16 __attribute__((ext_vector_type(16)));

// Q pre-scale: sm_scale (1/8) * log2(e)  -> allows p = exp2(s)
#define QSCALE 0.18033688011112042f

#if defined(__has_builtin)
#if __has_builtin(__builtin_amdgcn_exp2f)
#define EXP2F(x) __builtin_amdgcn_exp2f(x)
#endif
#endif
#ifndef EXP2F
#define EXP2F(x) exp2f(x)
#endif

#define GLDS16(g, l) __builtin_amdgcn_global_load_lds( \
    (__attribute__((address_space(1))) void*)(g),      \
    (__attribute__((address_space(3))) void*)(l), 16, 0, 0)

// ---------------- fp32 -> bf16 convert: x + 4 weights in ONE launch ----------------
__global__ __launch_bounds__(256)
void cvt_all(const float* __restrict__ x,  const float* __restrict__ Wq,
             const float* __restrict__ Wk, const float* __restrict__ Wv,
             const float* __restrict__ Wo, __bf16* __restrict__ dst) {
    size_t g = ((size_t)blockIdx.x * 256 + threadIdx.x) * 8;
    const float* s;
    size_t off;
    const size_t NX = (size_t)NTOK * DM;   // 4M
    if (g < NX) { s = x; off = g; }
    else {
        size_t gg = g - NX;
        int w = (int)(gg >> 20);           // 1M-element segments
        off = gg & ((1u << 20) - 1);
        s = (w == 0) ? Wq : (w == 1) ? Wk : (w == 2) ? Wv : Wo;
    }
    float4 a = *(const float4*)(s + off);
    float4 b = *(const float4*)(s + off + 4);
    bf16x8 v;
    v[0] = (__bf16)a.x; v[1] = (__bf16)a.y; v[2] = (__bf16)a.z; v[3] = (__bf16)a.w;
    v[4] = (__bf16)b.x; v[5] = (__bf16)b.y; v[6] = (__bf16)b.z; v[7] = (__bf16)b.w;
    *(bf16x8*)(dst + g) = v;
}

// =====================================================================
// bf16 MFMA GEMM (R1 structure: measured best for non-attn).
// C[m,n] = sum_k A[m,k] * B[n,k], 128x128 tile, BK=32.
// Double-buffered LDS staging; next-tile global_load_lds issued BEFORE
// current-tile compute; ONE barrier per K-step. Row-major LDS staging
// (linear global_load_lds dest, 64B-coalesced source — do NOT permute
// the source: R2 measured +12.7us from 16B-scattered source).
// MODE 0 (QKV, grid z) with LDS-transpose epilogue (packed 16B stores):
//   z=0: A=Wq, B=x (m=hd, n=token) -> Q[b,h,t,d] * QSCALE
//   z=1: A=Wk, B=x                  -> K[b,h,t,d]
//   z=2: A=x,  B=Wv (m=token, n=hd) -> Vt[b,h,d,t]
// MODE 1 (out-proj): A=Zm (m=token), B=Wo (n=Dout) -> out[t][D] fp32.
//   Bijective XCD swizzle: XCD c owns m-rows [512c,512c+512) -> per-XCD
//   working set 1MB Zm + 2MB Wo = 3MB <= 4MB L2 (1 block/CU kernel is
//   latency-exposed; natural mapping thrashes L2 with 8.25MB/XCD).
// =====================================================================
#define LSTR 136   // LDS transpose stride (16B-aligned rows, conflict-free)
#define DBUF 8192  // elems per staging buffer (As 4096 + Bs 4096)

template<int MODE>
__global__ __launch_bounds__(256)
void gemm_bf16(const __bf16* __restrict__ X,
               const __bf16* __restrict__ W0, const __bf16* __restrict__ W1,
               const __bf16* __restrict__ W2,
               __bf16* __restrict__ Oq, __bf16* __restrict__ Ok,
               __bf16* __restrict__ Ovt, float* __restrict__ Of)
{
    const int z = (MODE == 0) ? blockIdx.z : 3;
    const __bf16 *A, *B;
    int m0, n0;
    if (MODE == 0 && z < 2) {        // W·x^T : m=hd(1024), n=token(4096)
        A = z ? W1 : W0; B = X;
        m0 = blockIdx.y * 128; n0 = blockIdx.x * 128;
    } else if (MODE == 0) {          // x·Wv^T : m=token, n=hd
        A = X; B = W2;
        m0 = blockIdx.x * 128; n0 = blockIdx.y * 128;
    } else {                         // Zm·Wo^T : m=token(4096), n=Dout(1024)
        A = X; B = W0;
        int f = blockIdx.x + 8 * blockIdx.y;   // 0..255 dispatch order
        int c = f & 7, i = f >> 3;             // XCD c = f%8 (round-robin)
        m0 = (4 * c + (i & 3)) * 128;          // XCD c -> m-rows [512c,512c+512)
        n0 = (i >> 2) * 128;
    }

    // union: double-buffer staging (2 x (As 4K + Bs 4K) = 16K elems)
    //        / 128x136 transpose buffer (17408 elems)
    __shared__ __attribute__((aligned(16))) __bf16 smem[128 * LSTR];

    const int tid  = threadIdx.x;
    const int lane = tid & 63;
    const int wave = tid >> 6;
    const int wm = wave & 1, wn = wave >> 1;
    const int col = lane & 15, quad = lane >> 4;

    const __bf16* Ag = A + (size_t)(m0 + (tid >> 2)) * DM + (tid & 3) * 8;
    const __bf16* Bg = B + (size_t)(n0 + (tid >> 2)) * DM + (tid & 3) * 8;
    __bf16* lA = smem + tid * 8;            // As slot in buffer 0
    __bf16* lB = smem + 4096 + tid * 8;     // Bs slot in buffer 0

    f32x4 acc[4][4];
#pragma unroll
    for (int i = 0; i < 4; ++i)
#pragma unroll
        for (int j = 0; j < 4; ++j)
#pragma unroll
            for (int r = 0; r < 4; ++r) acc[i][j][r] = 0.0f;

    // ---- prologue: stage K-step 0 into buffer 0 ----
    GLDS16(Ag,                   lA);
    GLDS16(Ag + (size_t)64 * DM, lA + 2048);
    GLDS16(Bg,                   lB);
    GLDS16(Bg + (size_t)64 * DM, lB + 2048);
    __syncthreads();   // vmcnt(0) drained by compiler: buf0 ready

    const int nk = DM / 32;   // 32 K-steps
    for (int t = 0; t < nk; ++t) {
        const int cur = (t & 1) * DBUF;
        const int nxt = DBUF - cur;

        // issue next-tile loads FIRST — latency spans the compute below
        if (t + 1 < nk) {
            const int k1 = (t + 1) * 32;
            GLDS16(Ag + k1,                   lA + nxt);
            GLDS16(Ag + (size_t)64 * DM + k1, lA + nxt + 2048);
            GLDS16(Bg + k1,                   lB + nxt);
            GLDS16(Bg + (size_t)64 * DM + k1, lB + nxt + 2048);
        }

        const __bf16* Asr = smem + cur;
        const __bf16* Bsr = smem + cur + 4096;
        bf16x8 af[4], bfr[4];
#pragma unroll
        for (int i = 0; i < 4; ++i)
            af[i] = *(const bf16x8*)&Asr[(wm * 64 + i * 16 + col) * 32 + quad * 8];
#pragma unroll
        for (int j = 0; j < 4; ++j)
            bfr[j] = *(const bf16x8*)&Bsr[(wn * 64 + j * 16 + col) * 32 + quad * 8];
#pragma unroll
        for (int i = 0; i < 4; ++i)
#pragma unroll
            for (int j = 0; j < 4; ++j)
                acc[i][j] = __builtin_amdgcn_mfma_f32_16x16x32_bf16(af[i], bfr[j], acc[i][j], 0, 0, 0);

        // one barrier per K-step: drains next-tile vmcnt AFTER compute,
        // and guarantees all reads of buffer `cur` completed before it is
        // overwritten in iteration t+2.
        __syncthreads();
    }

    if (MODE == 1) {
        // scalar n-fastest fp32 stores: 16 lanes = 64B contiguous
#pragma unroll
        for (int i = 0; i < 4; ++i)
#pragma unroll
            for (int j = 0; j < 4; ++j) {
                const int mb = m0 + wm * 64 + i * 16 + quad * 4;
                const int n  = n0 + wn * 64 + j * 16 + col;
#pragma unroll
                for (int r = 0; r < 4; ++r)
                    Of[(size_t)(mb + r) * DM + n] = acc[i][j][r];
            }
        return;
    }

    // ---- MODE 0: LDS transpose -> packed global stores ----
    // (loop-trailing barrier already guarantees staging reads are done)
    const float sc = (z == 0) ? QSCALE : 1.0f;
#pragma unroll
    for (int i = 0; i < 4; ++i)
#pragma unroll
        for (int j = 0; j < 4; ++j) {
            const int ml = wm * 64 + i * 16 + quad * 4;
            const int nl = wn * 64 + j * 16 + col;
            bf16x4 pk;
#pragma unroll
            for (int r = 0; r < 4; ++r) pk[r] = (__bf16)(acc[i][j][r] * sc);
            *(bf16x4*)&smem[nl * LSTR + ml] = pk;   // Ls[n][m]
        }
    __syncthreads();

    // 128 rows x 16 chunks of 8 elems = 2048 chunks; 8 iterations x 256 thr
#pragma unroll
    for (int it = 0; it < 8; ++it) {
        int c   = tid + 256 * it;
        int row = c >> 4;          // n_local
        int ch  = (c & 15) * 8;    // m_local base
        bf16x8 v = *(const bf16x8*)&smem[row * LSTR + ch];
        if (z < 2) {
            // row = token, ch = hd: d-contiguous segments of Q/K[b,h,t,d]
            int t  = n0 + row;
            int b  = t >> 11; t &= 2047;
            int hd = m0 + ch;
            int h  = hd >> 6, d = hd & 63;
            *(bf16x8*)&((z ? Ok : Oq)[(((size_t)(b * 16 + h)) * TTOK + t) * 64 + d]) = v;
        } else {
            // row = hd, ch = token: t-contiguous segments of Vt[b,h,d,t]
            int hd = n0 + row;
            int h  = hd >> 6, d = hd & 63;
            int t  = m0 + ch;
            int b  = t >> 11; t &= 2047;
            *(bf16x8*)&Ovt[(((size_t)(b * 16 + h)) * 64 + d) * TTOK + t] = v;
        }
    }
}

// =====================================================================
// MFMA flash attention v7: R0's proven stride-72 layout, restructured:
//  - K/V LDS double-buffered -> ONE barrier per tile (was 2)
//  - Q frags loaded global->reg directly (no Q stage, no initial barrier)
//  - l computed on the VALU during the exp loop (drops the ones·P MFMA:
//    4 of 20 MFMA/tile = 20% of matrix-pipe time); one shfl_xor(32) at
//    the epilogue combines the h32 halves.
// 256 threads (4 waves), 128 q/block, 32 q/wave, 32x32x16 frags.
// S^T = K·Q^T (M=keys, N=q); p = exp2 (log2e folded into Q);
// O^T = V^T·P; exclusive-mod epilogue.
// LDS 54 KB: Ks/Vs 2x9K each + Ps 18K (per-wave 32-row P regions).
// =====================================================================
__global__ __launch_bounds__(256)
void attn_mfma(const __bf16* __restrict__ Qg, const __bf16* __restrict__ Kg,
               const __bf16* __restrict__ Vtg, __bf16* __restrict__ Zm)
{
    const int bh = blockIdx.y;
    const int q0 = blockIdx.x * 128;
    const size_t base = (size_t)bh * TTOK * 64;

    __shared__ __attribute__((aligned(16))) __bf16 Ks[2][64 * 72];
    __shared__ __attribute__((aligned(16))) __bf16 Vs[2][64 * 72];
    __shared__ __attribute__((aligned(16))) __bf16 Ps[128 * 72];

    const int tid  = threadIdx.x;
    const int lane = tid & 63, wave = tid >> 6;   // wave 0..3
    const int c32  = lane & 31, h32 = lane >> 5;

    // ---- Q frags: direct global -> regs (pre-scaled by QSCALE in GEMM) ----
    bf16x8 qf[4];
    const __bf16* qrow = Qg + base + (size_t)(q0 + wave * 32 + c32) * 64 + h32 * 8;
#pragma unroll
    for (int st = 0; st < 4; ++st)
        qf[st] = *(const bf16x8*)(qrow + st * 16);

    f32x16 O[2];
#pragma unroll
    for (int r = 0; r < 16; ++r) { O[0][r] = 0.0f; O[1][r] = 0.0f; }
    float lsum = 0.0f;

    const int rs = tid >> 2, soff = (tid & 3) * 16;   // 64 rows x 64, 2 b128/thread

    // ---- prologue: tile 0 -> regs -> buf0 ; tile 1 -> regs ----
    bf16x8 kr0 = *(const bf16x8*)(Kg  + base + (size_t)rs * 64 + soff);
    bf16x8 kr1 = *(const bf16x8*)(Kg  + base + (size_t)rs * 64 + soff + 8);
    bf16x8 vr0 = *(const bf16x8*)(Vtg + base + (size_t)rs * TTOK + soff);
    bf16x8 vr1 = *(const bf16x8*)(Vtg + base + (size_t)rs * TTOK + soff + 8);
    *(bf16x8*)&Ks[0][rs * 72 + soff]     = kr0;
    *(bf16x8*)&Ks[0][rs * 72 + soff + 8] = kr1;
    *(bf16x8*)&Vs[0][rs * 72 + soff]     = vr0;
    *(bf16x8*)&Vs[0][rs * 72 + soff + 8] = vr1;
    {
        const __bf16* kp = Kg  + base + (size_t)(64 + rs) * 64 + soff;
        const __bf16* vp = Vtg + base + (size_t)rs * TTOK + 64 + soff;
        kr0 = *(const bf16x8*)(kp); kr1 = *(const bf16x8*)(kp + 8);
        vr0 = *(const bf16x8*)(vp); vr1 = *(const bf16x8*)(vp + 8);
    }
    __syncthreads();

    // epilogue V snapshot coords: wave's q-rows live in key-tile kb_tgt
    const int kb_tgt = (q0 >> 6) + (wave >> 1);
    const int qo     = (wave & 1) * 32 + c32;
    float vq[2][16];

    for (int kb = 0; kb < TTOK / 64; ++kb) {
        const int cur = kb & 1;
        const __bf16* Kc = Ks[cur];
        const __bf16* Vc = Vs[cur];

        // ---- S^T = K·Q^T ----
        f32x16 s0, s1;
#pragma unroll
        for (int r = 0; r < 16; ++r) { s0[r] = 0.0f; s1[r] = 0.0f; }
#pragma unroll
        for (int st = 0; st < 4; ++st) {
            bf16x8 a0 = *(const bf16x8*)&Kc[(c32)      * 72 + h32 * 8 + st * 16];
            bf16x8 a1 = *(const bf16x8*)&Kc[(32 + c32) * 72 + h32 * 8 + st * 16];
            s0 = __builtin_amdgcn_mfma_f32_32x32x16_bf16(a0, qf[st], s0, 0, 0, 0);
            s1 = __builtin_amdgcn_mfma_f32_32x32x16_bf16(a1, qf[st], s1, 0, 0, 0);
        }

        // ---- p = exp2(s); lsum += p (VALU); write P[q][key] (b64) ----
#pragma unroll
        for (int kb2 = 0; kb2 < 2; ++kb2) {
#pragma unroll
            for (int g = 0; g < 4; ++g) {
                float p0 = EXP2F(kb2 ? s1[4 * g + 0] : s0[4 * g + 0]);
                float p1 = EXP2F(kb2 ? s1[4 * g + 1] : s0[4 * g + 1]);
                float p2 = EXP2F(kb2 ? s1[4 * g + 2] : s0[4 * g + 2]);
                float p3 = EXP2F(kb2 ? s1[4 * g + 3] : s0[4 * g + 3]);
                lsum += (p0 + p1) + (p2 + p3);
                bf16x4 pk;
                pk[0] = (__bf16)p0; pk[1] = (__bf16)p1;
                pk[2] = (__bf16)p2; pk[3] = (__bf16)p3;
                *(bf16x4*)&Ps[(wave * 32 + c32) * 72 + kb2 * 32 + g * 8 + h32 * 4] = pk;
            }
        }

        // ---- O^T += V^T·P ----
#pragma unroll
        for (int ks = 0; ks < 4; ++ks) {
            bf16x8 pf = *(const bf16x8*)&Ps[(wave * 32 + c32) * 72 + h32 * 8 + ks * 16];
            bf16x8 v0 = *(const bf16x8*)&Vc[(c32)      * 72 + h32 * 8 + ks * 16];
            bf16x8 v1 = *(const bf16x8*)&Vc[(32 + c32) * 72 + h32 * 8 + ks * 16];
            O[0] = __builtin_amdgcn_mfma_f32_32x32x16_bf16(v0, pf, O[0], 0, 0, 0);
            O[1] = __builtin_amdgcn_mfma_f32_32x32x16_bf16(v1, pf, O[1], 0, 0, 0);
        }

        // ---- snapshot own-q V column from LDS (wave-uniform branch) ----
        if (kb == kb_tgt) {
#pragma unroll
            for (int db = 0; db < 2; ++db)
#pragma unroll
                for (int rg = 0; rg < 16; ++rg) {
                    int d = db * 32 + (rg & 3) + 8 * (rg >> 2) + 4 * h32;
                    vq[db][rg] = (float)Vc[d * 72 + qo];
                }
        }

        // ---- stage tile kb+1 (in regs) -> other buffer ----
        __bf16* Kn = Ks[cur ^ 1];
        __bf16* Vn = Vs[cur ^ 1];
        *(bf16x8*)&Kn[rs * 72 + soff]     = kr0;
        *(bf16x8*)&Kn[rs * 72 + soff + 8] = kr1;
        *(bf16x8*)&Vn[rs * 72 + soff]     = vr0;
        *(bf16x8*)&Vn[rs * 72 + soff + 8] = vr1;

        // ---- prefetch tile kb+2 (consumed after next tile's compute) ----
        {
            int kbn = (kb + 2) & (TTOK / 64 - 1);
            const __bf16* kp = Kg  + base + (size_t)(kbn * 64 + rs) * 64 + soff;
            const __bf16* vp = Vtg + base + (size_t)rs * TTOK + kbn * 64 + soff;
            kr0 = *(const bf16x8*)(kp); kr1 = *(const bf16x8*)(kp + 8);
            vr0 = *(const bf16x8*)(vp); vr1 = *(const bf16x8*)(vp + 8);
        }

        // ONE barrier per tile: buf[cur^1] writes visible before tile kb+1
        // reads it; buf[cur] reads done before it is overwritten in kb+1.
        __syncthreads();
    }

    const float ltot = lsum + __shfl_xor(lsum, 32, 64);
    const float inv  = 1.0f / ltot;

    // ---- epilogue: Y = O/l ; exclusive output mod ; packed bf16 store ----
    const int b = bh >> 4, h = bh & 15;
    const int q = q0 + wave * 32 + c32;
    float y[2][16];
    float yv = 0.f, v2 = 0.f, yy = 0.f;
#pragma unroll
    for (int db = 0; db < 2; ++db)
#pragma unroll
        for (int rg = 0; rg < 16; ++rg) {
            float yval = O[db][rg] * inv;
            float vval = vq[db][rg];
            y[db][rg] = yval;
            yv += yval * vval; v2 += vval * vval; yy += yval * yval;
        }
    yv += __shfl_xor(yv, 32, 64);
    v2 += __shfl_xor(v2, 32, 64);
    yy += __shfl_xor(yy, 32, 64);
    float scl = (v2 > 0.0f) ? yv / fmaxf(v2, 1.1754943508222875e-38f) : 0.0f;
    float zz = 0.f;
    float zvv[2][16];
#pragma unroll
    for (int db = 0; db < 2; ++db)
#pragma unroll
        for (int rg = 0; rg < 16; ++rg) {
            zvv[db][rg] = y[db][rg] - scl * vq[db][rg];
            zz += zvv[db][rg] * zvv[db][rg];
        }
    zz += __shfl_xor(zz, 32, 64);
    float znorm = sqrtf(zz);
    float refn  = fmaxf(sqrtf(yy), sqrtf(v2));
    bool  wipe  = (v2 > 0.0f) && (znorm <= 1.1920928955078125e-07f * 64.0f * refn);
#pragma unroll
    for (int db = 0; db < 2; ++db)
#pragma unroll
        for (int g = 0; g < 4; ++g) {
            bf16x4 pk;
#pragma unroll
            for (int r = 0; r < 4; ++r)
                pk[r] = (__bf16)(wipe ? 0.0f : zvv[db][4 * g + r]);
            int d = db * 32 + 8 * g + 4 * h32;
            *(bf16x4*)&Zm[((size_t)(b * TTOK + q)) * DM + h * 64 + d] = pk;
        }
}

// =====================================================================
extern "C" void kernel_launch(void* const* d_in, const int* in_sizes, int n_in,
                              void* d_out, int out_size, void* d_ws, size_t ws_size,
                              hipStream_t stream) {
    const float* x  = (const float*)d_in[0];
    const float* Wq = (const float*)d_in[1];
    const float* Wk = (const float*)d_in[2];
    const float* Wv = (const float*)d_in[3];
    const float* Wo = (const float*)d_in[4];

    const size_t NX = (size_t)NTOK * DM;   // 4M
    const size_t NW = (size_t)DM * DM;     // 1M
    __bf16* xb  = (__bf16*)d_ws;
    __bf16* wqb = xb  + NX;
    __bf16* wkb = wqb + NW;
    __bf16* wvb = wkb + NW;
    __bf16* wob = wvb + NW;
    __bf16* Qb  = wob + NW;
    __bf16* Kb  = Qb  + NX;
    __bf16* Vtb = Kb  + NX;
    __bf16* Zmb = Vtb + NX;   // total 24M bf16 = 48 MB

    cvt_all<<<(NX + 4 * NW) / 2048, 256, 0, stream>>>(x, Wq, Wk, Wv, Wo, xb);

    // QKV: z0/z1 = Wq,Wk · x^T ; z2 = x · Wv^T  (LDS-transpose epilogues)
    gemm_bf16<0><<<dim3(32, 8, 3), 256, 0, stream>>>(
        xb, wqb, wkb, wvb, Qb, Kb, Vtb, nullptr);

    attn_mfma<<<dim3(TTOK / 128, 32), 256, 0, stream>>>(Qb, Kb, Vtb, Zmb);

    // out = Zm · Wo^T (m=token, n=Dout; XCD-swizzled grid)
    gemm_bf16<1><<<dim3(8, 32), 256, 0, stream>>>(
        Zmb, wob, nullptr, nullptr, nullptr, nullptr, nullptr, (float*)d_out);
}

// Round 5
// 185.686 us; speedup vs baseline: 1.1248x; 1.0129x over previous
//
#include <hip/hip_runtime.h>
#include <math.h>

#define DM   1024
#define TTOK 2048
#define NTOK 4096   // B*T

typedef __bf16 bf16x8 __attribute__((ext_vector_type(8)));
typedef __bf16 bf16x4 __attribute__((ext_vector_type(4)));
typedef __bf16 bf16x2 __attribute__((ext_vector_type(2)));
typedef float  f32x4  __attribute__((ext_vector_type(4)));
typedef float  f32x16 __attribute__((ext_vector_type(16)));

// Q pre-scale: sm_scale (1/8) * log2(e)  -> allows p = exp2(s)
#define QSCALE 0.18033688011112042f

#if defined(__has_builtin)
#if __has_builtin(__builtin_amdgcn_exp2f)
#define EXP2F(x) __builtin_amdgcn_exp2f(x)
#endif
#endif
#ifndef EXP2F
#define EXP2F(x) exp2f(x)
#endif

#define GLDS16(g, l) __builtin_amdgcn_global_load_lds( \
    (__attribute__((address_space(1))) void*)(g),      \
    (__attribute__((address_space(3))) void*)(l), 16, 0, 0)

// pack two f32 -> one dword of 2 bf16 (RNE, same rounding as (__bf16) cast)
__device__ __forceinline__ unsigned pk2(float a, float b) {
    bf16x2 t; t[0] = (__bf16)a; t[1] = (__bf16)b;
    return __builtin_bit_cast(unsigned, t);
}
union FU { unsigned u[4]; bf16x8 v; };

// ---------------- fp32 -> bf16 convert: x + 4 weights in ONE launch ----------------
__global__ __launch_bounds__(256)
void cvt_all(const float* __restrict__ x,  const float* __restrict__ Wq,
             const float* __restrict__ Wk, const float* __restrict__ Wv,
             const float* __restrict__ Wo, __bf16* __restrict__ dst) {
    size_t g = ((size_t)blockIdx.x * 256 + threadIdx.x) * 8;
    const float* s;
    size_t off;
    const size_t NX = (size_t)NTOK * DM;   // 4M
    if (g < NX) { s = x; off = g; }
    else {
        size_t gg = g - NX;
        int w = (int)(gg >> 20);           // 1M-element segments
        off = gg & ((1u << 20) - 1);
        s = (w == 0) ? Wq : (w == 1) ? Wk : (w == 2) ? Wv : Wo;
    }
    float4 a = *(const float4*)(s + off);
    float4 b = *(const float4*)(s + off + 4);
    bf16x8 v;
    v[0] = (__bf16)a.x; v[1] = (__bf16)a.y; v[2] = (__bf16)a.z; v[3] = (__bf16)a.w;
    v[4] = (__bf16)b.x; v[5] = (__bf16)b.y; v[6] = (__bf16)b.z; v[7] = (__bf16)b.w;
    *(bf16x8*)(dst + g) = v;
}

// =====================================================================
// bf16 MFMA GEMM, QKV only (proven R3 structure, untouched).
// C[m,n] = sum_k A[m,k] * B[n,k], 128x128 tile, BK=32.
// Double-buffered LDS staging; next-tile global_load_lds issued BEFORE
// current-tile compute; ONE barrier per K-step. Row-major LDS staging
// (linear global_load_lds dest, 64B-coalesced source).
//   z=0: A=Wq, B=x (m=hd, n=token) -> Q[b,h,t,d] * QSCALE
//   z=1: A=Wk, B=x                  -> K[b,h,t,d]
//   z=2: A=x,  B=Wv (m=token, n=hd) -> Vt[b,h,d,t]
// =====================================================================
#define LSTR 136   // LDS transpose stride (16B-aligned rows, conflict-free)
#define DBUF 8192  // elems per staging buffer (As 4096 + Bs 4096)

__global__ __launch_bounds__(256)
void gemm_qkv(const __bf16* __restrict__ X,
              const __bf16* __restrict__ W0, const __bf16* __restrict__ W1,
              const __bf16* __restrict__ W2,
              __bf16* __restrict__ Oq, __bf16* __restrict__ Ok,
              __bf16* __restrict__ Ovt)
{
    const int z = blockIdx.z;
    const __bf16 *A, *B;
    int m0, n0;
    if (z < 2) {                     // W·x^T : m=hd(1024), n=token(4096)
        A = z ? W1 : W0; B = X;
        m0 = blockIdx.y * 128; n0 = blockIdx.x * 128;
    } else {                         // x·Wv^T : m=token, n=hd
        A = X; B = W2;
        m0 = blockIdx.x * 128; n0 = blockIdx.y * 128;
    }

    // union: double-buffer staging (2 x (As 4K + Bs 4K) = 16K elems)
    //        / 128x136 transpose buffer (17408 elems)
    __shared__ __attribute__((aligned(16))) __bf16 smem[128 * LSTR];

    const int tid  = threadIdx.x;
    const int lane = tid & 63;
    const int wave = tid >> 6;
    const int wm = wave & 1, wn = wave >> 1;
    const int col = lane & 15, quad = lane >> 4;

    const __bf16* Ag = A + (size_t)(m0 + (tid >> 2)) * DM + (tid & 3) * 8;
    const __bf16* Bg = B + (size_t)(n0 + (tid >> 2)) * DM + (tid & 3) * 8;
    __bf16* lA = smem + tid * 8;            // As slot in buffer 0
    __bf16* lB = smem + 4096 + tid * 8;     // Bs slot in buffer 0

    f32x4 acc[4][4];
#pragma unroll
    for (int i = 0; i < 4; ++i)
#pragma unroll
        for (int j = 0; j < 4; ++j)
#pragma unroll
            for (int r = 0; r < 4; ++r) acc[i][j][r] = 0.0f;

    // ---- prologue: stage K-step 0 into buffer 0 ----
    GLDS16(Ag,                   lA);
    GLDS16(Ag + (size_t)64 * DM, lA + 2048);
    GLDS16(Bg,                   lB);
    GLDS16(Bg + (size_t)64 * DM, lB + 2048);
    __syncthreads();   // vmcnt(0) drained by compiler: buf0 ready

    const int nk = DM / 32;   // 32 K-steps
    for (int t = 0; t < nk; ++t) {
        const int cur = (t & 1) * DBUF;
        const int nxt = DBUF - cur;

        // issue next-tile loads FIRST — latency spans the compute below
        if (t + 1 < nk) {
            const int k1 = (t + 1) * 32;
            GLDS16(Ag + k1,                   lA + nxt);
            GLDS16(Ag + (size_t)64 * DM + k1, lA + nxt + 2048);
            GLDS16(Bg + k1,                   lB + nxt);
            GLDS16(Bg + (size_t)64 * DM + k1, lB + nxt + 2048);
        }

        const __bf16* Asr = smem + cur;
        const __bf16* Bsr = smem + cur + 4096;
        bf16x8 af[4], bfr[4];
#pragma unroll
        for (int i = 0; i < 4; ++i)
            af[i] = *(const bf16x8*)&Asr[(wm * 64 + i * 16 + col) * 32 + quad * 8];
#pragma unroll
        for (int j = 0; j < 4; ++j)
            bfr[j] = *(const bf16x8*)&Bsr[(wn * 64 + j * 16 + col) * 32 + quad * 8];
#pragma unroll
        for (int i = 0; i < 4; ++i)
#pragma unroll
            for (int j = 0; j < 4; ++j)
                acc[i][j] = __builtin_amdgcn_mfma_f32_16x16x32_bf16(af[i], bfr[j], acc[i][j], 0, 0, 0);

        __syncthreads();
    }

    // ---- LDS transpose -> packed global stores ----
    const float sc = (z == 0) ? QSCALE : 1.0f;
#pragma unroll
    for (int i = 0; i < 4; ++i)
#pragma unroll
        for (int j = 0; j < 4; ++j) {
            const int ml = wm * 64 + i * 16 + quad * 4;
            const int nl = wn * 64 + j * 16 + col;
            bf16x4 pk;
#pragma unroll
            for (int r = 0; r < 4; ++r) pk[r] = (__bf16)(acc[i][j][r] * sc);
            *(bf16x4*)&smem[nl * LSTR + ml] = pk;   // Ls[n][m]
        }
    __syncthreads();

    // 128 rows x 16 chunks of 8 elems = 2048 chunks; 8 iterations x 256 thr
#pragma unroll
    for (int it = 0; it < 8; ++it) {
        int c   = tid + 256 * it;
        int row = c >> 4;          // n_local
        int ch  = (c & 15) * 8;    // m_local base
        bf16x8 v = *(const bf16x8*)&smem[row * LSTR + ch];
        if (z < 2) {
            // row = token, ch = hd: d-contiguous segments of Q/K[b,h,t,d]
            int t  = n0 + row;
            int b  = t >> 11; t &= 2047;
            int hd = m0 + ch;
            int h  = hd >> 6, d = hd & 63;
            *(bf16x8*)&((z ? Ok : Oq)[(((size_t)(b * 16 + h)) * TTOK + t) * 64 + d]) = v;
        } else {
            // row = hd, ch = token: t-contiguous segments of Vt[b,h,d,t]
            int hd = n0 + row;
            int h  = hd >> 6, d = hd & 63;
            int t  = m0 + ch;
            int b  = t >> 11; t &= 2047;
            *(bf16x8*)&Ovt[(((size_t)(b * 16 + h)) * 64 + d) * TTOK + t] = v;
        }
    }
}

// =====================================================================
// out-proj: out[m][n] = sum_k Zm[m,k]*Wo[n,k], fp32 out.
// BM=64 x BN=128, BK=32 -> grid (8,64) = 512 blocks = 2 blocks/CU
// (was 1 at BM=128: zero TLP, latency fully exposed). Same dbuf +
// prefetch-first + 1-barrier structure. Bijective XCD swizzle: XCD c
// owns m-rows [512c,512c+512) -> 1MB Zm + 2MB Wo = 3MB <= 4MB L2.
// Per-wave: 64(m) x 32(n), acc[4][2].
// =====================================================================
#define ODBUF 6144   // elems per staging buffer (As 2048 + Bs 4096)

__global__ __launch_bounds__(256)
void gemm_oproj(const __bf16* __restrict__ X, const __bf16* __restrict__ Wo,
                float* __restrict__ Of)
{
    const int f = blockIdx.x + 8 * blockIdx.y;   // 0..511 dispatch-linear
    const int c = f & 7, i0 = f >> 3;            // XCD c (round-robin)
    const int m0 = (8 * c + (i0 & 7)) * 64;      // XCD c -> m-rows [512c,512c+512)
    const int n0 = (i0 >> 3) * 128;

    __shared__ __attribute__((aligned(16))) __bf16 smem[2 * ODBUF];

    const int tid  = threadIdx.x;
    const int lane = tid & 63;
    const int wave = tid >> 6;
    const int col = lane & 15, quad = lane >> 4;

    const __bf16* Ag = X  + (size_t)(m0 + (tid >> 2)) * DM + (tid & 3) * 8;  // 64 rows
    const __bf16* Bg = Wo + (size_t)(n0 + (tid >> 2)) * DM + (tid & 3) * 8;  // 128 rows
    __bf16* lA = smem + tid * 8;            // As: [64][32]
    __bf16* lB = smem + 2048 + tid * 8;     // Bs: [128][32]

    f32x4 acc[4][2];
#pragma unroll
    for (int i = 0; i < 4; ++i)
#pragma unroll
        for (int j = 0; j < 2; ++j)
#pragma unroll
            for (int r = 0; r < 4; ++r) acc[i][j][r] = 0.0f;

    GLDS16(Ag,                   lA);
    GLDS16(Bg,                   lB);
    GLDS16(Bg + (size_t)64 * DM, lB + 2048);
    __syncthreads();

    const int nk = DM / 32;
    for (int t = 0; t < nk; ++t) {
        const int cur = (t & 1) * ODBUF;
        const int nxt = ODBUF - cur;
        if (t + 1 < nk) {
            const int k1 = (t + 1) * 32;
            GLDS16(Ag + k1,                   lA + nxt);
            GLDS16(Bg + k1,                   lB + nxt);
            GLDS16(Bg + (size_t)64 * DM + k1, lB + nxt + 2048);
        }
        const __bf16* Asr = smem + cur;
        const __bf16* Bsr = smem + cur + 2048;
        bf16x8 af[4], bfr[2];
#pragma unroll
        for (int i = 0; i < 4; ++i)
            af[i] = *(const bf16x8*)&Asr[(i * 16 + col) * 32 + quad * 8];
#pragma unroll
        for (int j = 0; j < 2; ++j)
            bfr[j] = *(const bf16x8*)&Bsr[(wave * 32 + j * 16 + col) * 32 + quad * 8];
#pragma unroll
        for (int i = 0; i < 4; ++i)
#pragma unroll
            for (int j = 0; j < 2; ++j)
                acc[i][j] = __builtin_amdgcn_mfma_f32_16x16x32_bf16(af[i], bfr[j], acc[i][j], 0, 0, 0);
        __syncthreads();
    }

    // scalar n-fastest fp32 stores: 16 lanes = 64B contiguous
#pragma unroll
    for (int i = 0; i < 4; ++i)
#pragma unroll
        for (int j = 0; j < 2; ++j) {
            const int mb = m0 + i * 16 + quad * 4;
            const int n  = n0 + wave * 32 + j * 16 + col;
#pragma unroll
            for (int r = 0; r < 4; ++r)
                Of[(size_t)(mb + r) * DM + n] = acc[i][j][r];
        }
}

// =====================================================================
// MFMA flash attention v8 = v7 + T12 in-register P (no P LDS round-trip).
// 256 threads (4 waves), 128 q/block, 32 q/wave, 32x32x16 frags.
// S^T = K·Q^T leaves P lane-local: lane (c32,h32') holds
//   P[q=c32][key=32*kb2+8g+4*h32'+rr] at s_{kb2} reg 4g+rr.
// PV B-frag (dest lane h32, subtile ks) needs octet o=2ks+h32:
//   kb2=ks>>1, reg base 8*(ks&1) (low half, A0/A1) / +4 (high, B0/B1);
//   elems0..3 from h32'=0 lane, elems4..7 from h32'=1 lane -> one
//   shfl_xor(32) + cndmask merge assembles the frag in-register.
// Deletes per-tile ds_write_b64 x8 + ds_read_b128 x4 (serial chain) and
// the 18KB Ps buffer. l on VALU; exclusive-mod epilogue.
// LDS 36 KB: Ks/Vs double-buffered, ONE barrier/tile.
// =====================================================================
__global__ __launch_bounds__(256)
void attn_mfma(const __bf16* __restrict__ Qg, const __bf16* __restrict__ Kg,
               const __bf16* __restrict__ Vtg, __bf16* __restrict__ Zm)
{
    const int bh = blockIdx.y;
    const int q0 = blockIdx.x * 128;
    const size_t base = (size_t)bh * TTOK * 64;

    __shared__ __attribute__((aligned(16))) __bf16 Ks[2][64 * 72];
    __shared__ __attribute__((aligned(16))) __bf16 Vs[2][64 * 72];

    const int tid  = threadIdx.x;
    const int lane = tid & 63, wave = tid >> 6;   // wave 0..3
    const int c32  = lane & 31, h32 = lane >> 5;

    // ---- Q frags: direct global -> regs (pre-scaled by QSCALE in GEMM) ----
    bf16x8 qf[4];
    const __bf16* qrow = Qg + base + (size_t)(q0 + wave * 32 + c32) * 64 + h32 * 8;
#pragma unroll
    for (int st = 0; st < 4; ++st)
        qf[st] = *(const bf16x8*)(qrow + st * 16);

    f32x16 O[2];
#pragma unroll
    for (int r = 0; r < 16; ++r) { O[0][r] = 0.0f; O[1][r] = 0.0f; }
    float lsum = 0.0f;

    const int rs = tid >> 2, soff = (tid & 3) * 16;   // 64 rows x 64, 2 b128/thread

    // ---- prologue: tile 0 -> regs -> buf0 ; tile 1 -> regs ----
    bf16x8 kr0 = *(const bf16x8*)(Kg  + base + (size_t)rs * 64 + soff);
    bf16x8 kr1 = *(const bf16x8*)(Kg  + base + (size_t)rs * 64 + soff + 8);
    bf16x8 vr0 = *(const bf16x8*)(Vtg + base + (size_t)rs * TTOK + soff);
    bf16x8 vr1 = *(const bf16x8*)(Vtg + base + (size_t)rs * TTOK + soff + 8);
    *(bf16x8*)&Ks[0][rs * 72 + soff]     = kr0;
    *(bf16x8*)&Ks[0][rs * 72 + soff + 8] = kr1;
    *(bf16x8*)&Vs[0][rs * 72 + soff]     = vr0;
    *(bf16x8*)&Vs[0][rs * 72 + soff + 8] = vr1;
    {
        const __bf16* kp = Kg  + base + (size_t)(64 + rs) * 64 + soff;
        const __bf16* vp = Vtg + base + (size_t)rs * TTOK + 64 + soff;
        kr0 = *(const bf16x8*)(kp); kr1 = *(const bf16x8*)(kp + 8);
        vr0 = *(const bf16x8*)(vp); vr1 = *(const bf16x8*)(vp + 8);
    }
    __syncthreads();

    // epilogue V snapshot coords: wave's q-rows live in key-tile kb_tgt
    const int kb_tgt = (q0 >> 6) + (wave >> 1);
    const int qo     = (wave & 1) * 32 + c32;
    float vq[2][16];

    for (int kb = 0; kb < TTOK / 64; ++kb) {
        const int cur = kb & 1;
        const __bf16* Kc = Ks[cur];
        const __bf16* Vc = Vs[cur];

        // ---- S^T = K·Q^T ----
        f32x16 s0, s1;
#pragma unroll
        for (int r = 0; r < 16; ++r) { s0[r] = 0.0f; s1[r] = 0.0f; }
#pragma unroll
        for (int st = 0; st < 4; ++st) {
            bf16x8 a0 = *(const bf16x8*)&Kc[(c32)      * 72 + h32 * 8 + st * 16];
            bf16x8 a1 = *(const bf16x8*)&Kc[(32 + c32) * 72 + h32 * 8 + st * 16];
            s0 = __builtin_amdgcn_mfma_f32_32x32x16_bf16(a0, qf[st], s0, 0, 0, 0);
            s1 = __builtin_amdgcn_mfma_f32_32x32x16_bf16(a1, qf[st], s1, 0, 0, 0);
        }

        // ---- p = exp2(s); lsum (VALU); build PV B-frags in-register ----
        float pl0[16], pl1[16];
#pragma unroll
        for (int r = 0; r < 16; ++r) { pl0[r] = EXP2F(s0[r]); pl1[r] = EXP2F(s1[r]); }
#pragma unroll
        for (int r = 0; r < 16; ++r) lsum += pl0[r] + pl1[r];

        bf16x8 pf[4];
#pragma unroll
        for (int ks = 0; ks < 4; ++ks) {
            const float* pl = (ks & 2) ? pl1 : pl0;   // compile-time after unroll
            const int rb = (ks & 1) * 8;
            // A-pack: regs rb..rb+3  (low half of octet, held by h32'=0)
            // B-pack: regs rb+4..rb+7 (high half of octet, held by h32'=1)
            unsigned A0 = pk2(pl[rb + 0], pl[rb + 1]);
            unsigned A1 = pk2(pl[rb + 2], pl[rb + 3]);
            unsigned B0 = pk2(pl[rb + 4], pl[rb + 5]);
            unsigned B1 = pk2(pl[rb + 6], pl[rb + 7]);
            unsigned s0w = h32 ? A0 : B0;           // send what partner needs
            unsigned s1w = h32 ? A1 : B1;
            unsigned r0 = __shfl_xor(s0w, 32, 64);
            unsigned r1 = __shfl_xor(s1w, 32, 64);
            FU fu;
            fu.u[0] = h32 ? r0 : A0;
            fu.u[1] = h32 ? r1 : A1;
            fu.u[2] = h32 ? B0 : r0;
            fu.u[3] = h32 ? B1 : r1;
            pf[ks] = fu.v;
        }

        // ---- O^T += V^T·P ----
#pragma unroll
        for (int ks = 0; ks < 4; ++ks) {
            bf16x8 v0 = *(const bf16x8*)&Vc[(c32)      * 72 + h32 * 8 + ks * 16];
            bf16x8 v1 = *(const bf16x8*)&Vc[(32 + c32) * 72 + h32 * 8 + ks * 16];
            O[0] = __builtin_amdgcn_mfma_f32_32x32x16_bf16(v0, pf[ks], O[0], 0, 0, 0);
            O[1] = __builtin_amdgcn_mfma_f32_32x32x16_bf16(v1, pf[ks], O[1], 0, 0, 0);
        }

        // ---- snapshot own-q V column from LDS (wave-uniform branch) ----
        if (kb == kb_tgt) {
#pragma unroll
            for (int db = 0; db < 2; ++db)
#pragma unroll
                for (int rg = 0; rg < 16; ++rg) {
                    int d = db * 32 + (rg & 3) + 8 * (rg >> 2) + 4 * h32;
                    vq[db][rg] = (float)Vc[d * 72 + qo];
                }
        }

        // ---- stage tile kb+1 (in regs) -> other buffer ----
        __bf16* Kn = Ks[cur ^ 1];
        __bf16* Vn = Vs[cur ^ 1];
        *(bf16x8*)&Kn[rs * 72 + soff]     = kr0;
        *(bf16x8*)&Kn[rs * 72 + soff + 8] = kr1;
        *(bf16x8*)&Vn[rs * 72 + soff]     = vr0;
        *(bf16x8*)&Vn[rs * 72 + soff + 8] = vr1;

        // ---- prefetch tile kb+2 (consumed after next tile's compute) ----
        {
            int kbn = (kb + 2) & (TTOK / 64 - 1);
            const __bf16* kp = Kg  + base + (size_t)(kbn * 64 + rs) * 64 + soff;
            const __bf16* vp = Vtg + base + (size_t)rs * TTOK + kbn * 64 + soff;
            kr0 = *(const bf16x8*)(kp); kr1 = *(const bf16x8*)(kp + 8);
            vr0 = *(const bf16x8*)(vp); vr1 = *(const bf16x8*)(vp + 8);
        }

        // ONE barrier per tile
        __syncthreads();
    }

    const float ltot = lsum + __shfl_xor(lsum, 32, 64);
    const float inv  = 1.0f / ltot;

    // ---- epilogue: Y = O/l ; exclusive output mod ; packed bf16 store ----
    const int b = bh >> 4, h = bh & 15;
    const int q = q0 + wave * 32 + c32;
    float y[2][16];
    float yv = 0.f, v2 = 0.f, yy = 0.f;
#pragma unroll
    for (int db = 0; db < 2; ++db)
#pragma unroll
        for (int rg = 0; rg < 16; ++rg) {
            float yval = O[db][rg] * inv;
            float vval = vq[db][rg];
            y[db][rg] = yval;
            yv += yval * vval; v2 += vval * vval; yy += yval * yval;
        }
    yv += __shfl_xor(yv, 32, 64);
    v2 += __shfl_xor(v2, 32, 64);
    yy += __shfl_xor(yy, 32, 64);
    float scl = (v2 > 0.0f) ? yv / fmaxf(v2, 1.1754943508222875e-38f) : 0.0f;
    float zz = 0.f;
    float zvv[2][16];
#pragma unroll
    for (int db = 0; db < 2; ++db)
#pragma unroll
        for (int rg = 0; rg < 16; ++rg) {
            zvv[db][rg] = y[db][rg] - scl * vq[db][rg];
            zz += zvv[db][rg] * zvv[db][rg];
        }
    zz += __shfl_xor(zz, 32, 64);
    float znorm = sqrtf(zz);
    float refn  = fmaxf(sqrtf(yy), sqrtf(v2));
    bool  wipe  = (v2 > 0.0f) && (znorm <= 1.1920928955078125e-07f * 64.0f * refn);
#pragma unroll
    for (int db = 0; db < 2; ++db)
#pragma unroll
        for (int g = 0; g < 4; ++g) {
            bf16x4 pk;
#pragma unroll
            for (int r = 0; r < 4; ++r)
                pk[r] = (__bf16)(wipe ? 0.0f : zvv[db][4 * g + r]);
            int d = db * 32 + 8 * g + 4 * h32;
            *(bf16x4*)&Zm[((size_t)(b * TTOK + q)) * DM + h * 64 + d] = pk;
        }
}

// =====================================================================
extern "C" void kernel_launch(void* const* d_in, const int* in_sizes, int n_in,
                              void* d_out, int out_size, void* d_ws, size_t ws_size,
                              hipStream_t stream) {
    const float* x  = (const float*)d_in[0];
    const float* Wq = (const float*)d_in[1];
    const float* Wk = (const float*)d_in[2];
    const float* Wv = (const float*)d_in[3];
    const float* Wo = (const float*)d_in[4];

    const size_t NX = (size_t)NTOK * DM;   // 4M
    const size_t NW = (size_t)DM * DM;     // 1M
    __bf16* xb  = (__bf16*)d_ws;
    __bf16* wqb = xb  + NX;
    __bf16* wkb = wqb + NW;
    __bf16* wvb = wkb + NW;
    __bf16* wob = wvb + NW;
    __bf16* Qb  = wob + NW;
    __bf16* Kb  = Qb  + NX;
    __bf16* Vtb = Kb  + NX;
    __bf16* Zmb = Vtb + NX;   // total 24M bf16 = 48 MB

    cvt_all<<<(NX + 4 * NW) / 2048, 256, 0, stream>>>(x, Wq, Wk, Wv, Wo, xb);

    // QKV: z0/z1 = Wq,Wk · x^T ; z2 = x · Wv^T  (LDS-transpose epilogues)
    gemm_qkv<<<dim3(32, 8, 3), 256, 0, stream>>>(
        xb, wqb, wkb, wvb, Qb, Kb, Vtb);

    attn_mfma<<<dim3(TTOK / 128, 32), 256, 0, stream>>>(Qb, Kb, Vtb, Zmb);

    // out = Zm · Wo^T (BM=64 x BN=128, 512 blocks, XCD-swizzled)
    gemm_oproj<<<dim3(8, 64), 256, 0, stream>>>(Zmb, wob, (float*)d_out);
}

// Round 6
// 184.551 us; speedup vs baseline: 1.1317x; 1.0062x over previous
//
#include <hip/hip_runtime.h>
#include <math.h>

#define DM   1024
#define TTOK 2048
#define NTOK 4096   // B*T

typedef __bf16 bf16x8 __attribute__((ext_vector_type(8)));
typedef __bf16 bf16x4 __attribute__((ext_vector_type(4)));
typedef __bf16 bf16x2 __attribute__((ext_vector_type(2)));
typedef float  f32x4  __attribute__((ext_vector_type(4)));
typedef float  f32x16 __attribute__((ext_vector_type(16)));

// Q pre-scale: sm_scale (1/8) * log2(e)  -> allows p = exp2(s)
#define QSCALE 0.18033688011112042f

#if defined(__has_builtin)
#if __has_builtin(__builtin_amdgcn_exp2f)
#define EXP2F(x) __builtin_amdgcn_exp2f(x)
#endif
#endif
#ifndef EXP2F
#define EXP2F(x) exp2f(x)
#endif

#define GLDS16(g, l) __builtin_amdgcn_global_load_lds( \
    (__attribute__((address_space(1))) void*)(g),      \
    (__attribute__((address_space(3))) void*)(l), 16, 0, 0)

// pack two f32 -> one dword of 2 bf16 (RNE, same rounding as (__bf16) cast)
__device__ __forceinline__ unsigned pk2(float a, float b) {
    bf16x2 t; t[0] = (__bf16)a; t[1] = (__bf16)b;
    return __builtin_bit_cast(unsigned, t);
}
union FU { unsigned u[4]; bf16x8 v; };

// ---------------- fp32 -> bf16 convert: x + 4 weights in ONE launch ----------------
__global__ __launch_bounds__(256)
void cvt_all(const float* __restrict__ x,  const float* __restrict__ Wq,
             const float* __restrict__ Wk, const float* __restrict__ Wv,
             const float* __restrict__ Wo, __bf16* __restrict__ dst) {
    size_t g = ((size_t)blockIdx.x * 256 + threadIdx.x) * 8;
    const float* s;
    size_t off;
    const size_t NX = (size_t)NTOK * DM;   // 4M
    if (g < NX) { s = x; off = g; }
    else {
        size_t gg = g - NX;
        int w = (int)(gg >> 20);           // 1M-element segments
        off = gg & ((1u << 20) - 1);
        s = (w == 0) ? Wq : (w == 1) ? Wk : (w == 2) ? Wv : Wo;
    }
    float4 a = *(const float4*)(s + off);
    float4 b = *(const float4*)(s + off + 4);
    bf16x8 v;
    v[0] = (__bf16)a.x; v[1] = (__bf16)a.y; v[2] = (__bf16)a.z; v[3] = (__bf16)a.w;
    v[4] = (__bf16)b.x; v[5] = (__bf16)b.y; v[6] = (__bf16)b.z; v[7] = (__bf16)b.w;
    *(bf16x8*)(dst + g) = v;
}

// =====================================================================
// bf16 MFMA GEMM, QKV only (proven R3 structure, untouched).
// C[m,n] = sum_k A[m,k] * B[n,k], 128x128 tile, BK=32.
// Double-buffered LDS staging; next-tile global_load_lds issued BEFORE
// current-tile compute; ONE barrier per K-step. Row-major LDS staging
// (linear global_load_lds dest, 64B-coalesced source).
//   z=0: A=Wq, B=x (m=hd, n=token) -> Q[b,h,t,d] * QSCALE
//   z=1: A=Wk, B=x                  -> K[b,h,t,d]
//   z=2: A=x,  B=Wv (m=token, n=hd) -> Vt[b,h,d,t]
// =====================================================================
#define LSTR 136   // LDS transpose stride (16B-aligned rows, conflict-free)
#define DBUF 8192  // elems per staging buffer (As 4096 + Bs 4096)

__global__ __launch_bounds__(256)
void gemm_qkv(const __bf16* __restrict__ X,
              const __bf16* __restrict__ W0, const __bf16* __restrict__ W1,
              const __bf16* __restrict__ W2,
              __bf16* __restrict__ Oq, __bf16* __restrict__ Ok,
              __bf16* __restrict__ Ovt)
{
    const int z = blockIdx.z;
    const __bf16 *A, *B;
    int m0, n0;
    if (z < 2) {                     // W·x^T : m=hd(1024), n=token(4096)
        A = z ? W1 : W0; B = X;
        m0 = blockIdx.y * 128; n0 = blockIdx.x * 128;
    } else {                         // x·Wv^T : m=token, n=hd
        A = X; B = W2;
        m0 = blockIdx.x * 128; n0 = blockIdx.y * 128;
    }

    // union: double-buffer staging (2 x (As 4K + Bs 4K) = 16K elems)
    //        / 128x136 transpose buffer (17408 elems)
    __shared__ __attribute__((aligned(16))) __bf16 smem[128 * LSTR];

    const int tid  = threadIdx.x;
    const int lane = tid & 63;
    const int wave = tid >> 6;
    const int wm = wave & 1, wn = wave >> 1;
    const int col = lane & 15, quad = lane >> 4;

    const __bf16* Ag = A + (size_t)(m0 + (tid >> 2)) * DM + (tid & 3) * 8;
    const __bf16* Bg = B + (size_t)(n0 + (tid >> 2)) * DM + (tid & 3) * 8;
    __bf16* lA = smem + tid * 8;            // As slot in buffer 0
    __bf16* lB = smem + 4096 + tid * 8;     // Bs slot in buffer 0

    f32x4 acc[4][4];
#pragma unroll
    for (int i = 0; i < 4; ++i)
#pragma unroll
        for (int j = 0; j < 4; ++j)
#pragma unroll
            for (int r = 0; r < 4; ++r) acc[i][j][r] = 0.0f;

    // ---- prologue: stage K-step 0 into buffer 0 ----
    GLDS16(Ag,                   lA);
    GLDS16(Ag + (size_t)64 * DM, lA + 2048);
    GLDS16(Bg,                   lB);
    GLDS16(Bg + (size_t)64 * DM, lB + 2048);
    __syncthreads();   // vmcnt(0) drained by compiler: buf0 ready

    const int nk = DM / 32;   // 32 K-steps
    for (int t = 0; t < nk; ++t) {
        const int cur = (t & 1) * DBUF;
        const int nxt = DBUF - cur;

        // issue next-tile loads FIRST — latency spans the compute below
        if (t + 1 < nk) {
            const int k1 = (t + 1) * 32;
            GLDS16(Ag + k1,                   lA + nxt);
            GLDS16(Ag + (size_t)64 * DM + k1, lA + nxt + 2048);
            GLDS16(Bg + k1,                   lB + nxt);
            GLDS16(Bg + (size_t)64 * DM + k1, lB + nxt + 2048);
        }

        const __bf16* Asr = smem + cur;
        const __bf16* Bsr = smem + cur + 4096;
        bf16x8 af[4], bfr[4];
#pragma unroll
        for (int i = 0; i < 4; ++i)
            af[i] = *(const bf16x8*)&Asr[(wm * 64 + i * 16 + col) * 32 + quad * 8];
#pragma unroll
        for (int j = 0; j < 4; ++j)
            bfr[j] = *(const bf16x8*)&Bsr[(wn * 64 + j * 16 + col) * 32 + quad * 8];
#pragma unroll
        for (int i = 0; i < 4; ++i)
#pragma unroll
            for (int j = 0; j < 4; ++j)
                acc[i][j] = __builtin_amdgcn_mfma_f32_16x16x32_bf16(af[i], bfr[j], acc[i][j], 0, 0, 0);

        __syncthreads();
    }

    // ---- LDS transpose -> packed global stores ----
    const float sc = (z == 0) ? QSCALE : 1.0f;
#pragma unroll
    for (int i = 0; i < 4; ++i)
#pragma unroll
        for (int j = 0; j < 4; ++j) {
            const int ml = wm * 64 + i * 16 + quad * 4;
            const int nl = wn * 64 + j * 16 + col;
            bf16x4 pk;
#pragma unroll
            for (int r = 0; r < 4; ++r) pk[r] = (__bf16)(acc[i][j][r] * sc);
            *(bf16x4*)&smem[nl * LSTR + ml] = pk;   // Ls[n][m]
        }
    __syncthreads();

    // 128 rows x 16 chunks of 8 elems = 2048 chunks; 8 iterations x 256 thr
#pragma unroll
    for (int it = 0; it < 8; ++it) {
        int c   = tid + 256 * it;
        int row = c >> 4;          // n_local
        int ch  = (c & 15) * 8;    // m_local base
        bf16x8 v = *(const bf16x8*)&smem[row * LSTR + ch];
        if (z < 2) {
            // row = token, ch = hd: d-contiguous segments of Q/K[b,h,t,d]
            int t  = n0 + row;
            int b  = t >> 11; t &= 2047;
            int hd = m0 + ch;
            int h  = hd >> 6, d = hd & 63;
            *(bf16x8*)&((z ? Ok : Oq)[(((size_t)(b * 16 + h)) * TTOK + t) * 64 + d]) = v;
        } else {
            // row = hd, ch = token: t-contiguous segments of Vt[b,h,d,t]
            int hd = n0 + row;
            int h  = hd >> 6, d = hd & 63;
            int t  = m0 + ch;
            int b  = t >> 11; t &= 2047;
            *(bf16x8*)&Ovt[(((size_t)(b * 16 + h)) * 64 + d) * TTOK + t] = v;
        }
    }
}

// =====================================================================
// out-proj: out[m][n] = sum_k Zm[m,k]*Wo[n,k], fp32 out.
// BM=64 x BN=128, BK=32 -> grid (8,64) = 512 blocks = 2 blocks/CU.
// Bijective XCD swizzle: XCD c owns m-rows [512c,512c+512).
// (unchanged from R5 for attribution)
// =====================================================================
#define ODBUF 6144   // elems per staging buffer (As 2048 + Bs 4096)

__global__ __launch_bounds__(256)
void gemm_oproj(const __bf16* __restrict__ X, const __bf16* __restrict__ Wo,
                float* __restrict__ Of)
{
    const int f = blockIdx.x + 8 * blockIdx.y;   // 0..511 dispatch-linear
    const int c = f & 7, i0 = f >> 3;            // XCD c (round-robin)
    const int m0 = (8 * c + (i0 & 7)) * 64;      // XCD c -> m-rows [512c,512c+512)
    const int n0 = (i0 >> 3) * 128;

    __shared__ __attribute__((aligned(16))) __bf16 smem[2 * ODBUF];

    const int tid  = threadIdx.x;
    const int lane = tid & 63;
    const int wave = tid >> 6;
    const int col = lane & 15, quad = lane >> 4;

    const __bf16* Ag = X  + (size_t)(m0 + (tid >> 2)) * DM + (tid & 3) * 8;  // 64 rows
    const __bf16* Bg = Wo + (size_t)(n0 + (tid >> 2)) * DM + (tid & 3) * 8;  // 128 rows
    __bf16* lA = smem + tid * 8;            // As: [64][32]
    __bf16* lB = smem + 2048 + tid * 8;     // Bs: [128][32]

    f32x4 acc[4][2];
#pragma unroll
    for (int i = 0; i < 4; ++i)
#pragma unroll
        for (int j = 0; j < 2; ++j)
#pragma unroll
            for (int r = 0; r < 4; ++r) acc[i][j][r] = 0.0f;

    GLDS16(Ag,                   lA);
    GLDS16(Bg,                   lB);
    GLDS16(Bg + (size_t)64 * DM, lB + 2048);
    __syncthreads();

    const int nk = DM / 32;
    for (int t = 0; t < nk; ++t) {
        const int cur = (t & 1) * ODBUF;
        const int nxt = ODBUF - cur;
        if (t + 1 < nk) {
            const int k1 = (t + 1) * 32;
            GLDS16(Ag + k1,                   lA + nxt);
            GLDS16(Bg + k1,                   lB + nxt);
            GLDS16(Bg + (size_t)64 * DM + k1, lB + nxt + 2048);
        }
        const __bf16* Asr = smem + cur;
        const __bf16* Bsr = smem + cur + 2048;
        bf16x8 af[4], bfr[2];
#pragma unroll
        for (int i = 0; i < 4; ++i)
            af[i] = *(const bf16x8*)&Asr[(i * 16 + col) * 32 + quad * 8];
#pragma unroll
        for (int j = 0; j < 2; ++j)
            bfr[j] = *(const bf16x8*)&Bsr[(wave * 32 + j * 16 + col) * 32 + quad * 8];
#pragma unroll
        for (int i = 0; i < 4; ++i)
#pragma unroll
            for (int j = 0; j < 2; ++j)
                acc[i][j] = __builtin_amdgcn_mfma_f32_16x16x32_bf16(af[i], bfr[j], acc[i][j], 0, 0, 0);
        __syncthreads();
    }

    // scalar n-fastest fp32 stores: 16 lanes = 64B contiguous
#pragma unroll
    for (int i = 0; i < 4; ++i)
#pragma unroll
        for (int j = 0; j < 2; ++j) {
            const int mb = m0 + i * 16 + quad * 4;
            const int n  = n0 + wave * 32 + j * 16 + col;
#pragma unroll
            for (int r = 0; r < 4; ++r)
                Of[(size_t)(mb + r) * DM + n] = acc[i][j][r];
        }
}

// =====================================================================
// MFMA flash attention v9: KV-SPLIT 8-WAVE BLOCKS (occupancy fix).
// R5 evidence: conflicts=0, MFMA 24%, VALU 38%, Occupancy 16% -> the
// serial QK->exp->pack->PV chain is latency-exposed at 2 waves/SIMD.
// v9: 512 threads; waves 0-3 = q-sets x keys [0,1024), waves 4-7 =
// same q-sets x keys [1024,2048) -> 2 blocks/CU = 4 waves/SIMD.
// exp2-softmax (no running max) is additive: O=O_lo+O_hi, l=l_lo+l_hi;
// combine through LDS after the loop (reuses K/V space). vq re-read
// from global Vt at epilogue (frees 32 VGPR from the loop).
// In-register P (R5, verified); stride-72 K/V layout (0 conflicts).
// LDS 72 KB: [half][K/V][2 buf][64*72]. __launch_bounds__(512,4).
// =====================================================================
__global__ __launch_bounds__(512, 4)
void attn_mfma(const __bf16* __restrict__ Qg, const __bf16* __restrict__ Kg,
               const __bf16* __restrict__ Vtg, __bf16* __restrict__ Zm)
{
    const int bh = blockIdx.y;
    const int q0 = blockIdx.x * 128;
    const size_t base = (size_t)bh * TTOK * 64;

    // [half][kv][buf][64*72]; reused as float combine buffer post-loop
    __shared__ __attribute__((aligned(16))) __bf16 lds[2][2][2][64 * 72];

    const int tid  = threadIdx.x;          // 0..511
    const int lane = tid & 63;
    const int wave = tid >> 6;             // 0..7
    const int half = wave >> 2;            // key range half
    const int qw   = wave & 3;             // q-set
    const int c32  = lane & 31, h32 = lane >> 5;

    // ---- Q frags: direct global -> regs (pre-scaled by QSCALE in GEMM) ----
    bf16x8 qf[4];
    const __bf16* qrow = Qg + base + (size_t)(q0 + qw * 32 + c32) * 64 + h32 * 8;
#pragma unroll
    for (int st = 0; st < 4; ++st)
        qf[st] = *(const bf16x8*)(qrow + st * 16);

    f32x16 O[2];
#pragma unroll
    for (int r = 0; r < 16; ++r) { O[0][r] = 0.0f; O[1][r] = 0.0f; }
    float lsum = 0.0f;

    // staging coords within this half's 256-thread group
    const int tid8 = tid & 255;
    const int rs   = tid8 >> 2;            // 0..63
    const int soff = (tid8 & 3) * 16;
    const int kb0  = half * 1024;          // key base for this half

    // ---- prologue: tile 0 -> buf0 ; tile 1 -> regs ----
    {
        const __bf16* kp = Kg  + base + (size_t)(kb0 + rs) * 64 + soff;
        const __bf16* vp = Vtg + base + (size_t)rs * TTOK + kb0 + soff;
        bf16x8 k0 = *(const bf16x8*)(kp);
        bf16x8 k1 = *(const bf16x8*)(kp + 8);
        bf16x8 v0 = *(const bf16x8*)(vp);
        bf16x8 v1 = *(const bf16x8*)(vp + 8);
        *(bf16x8*)&lds[half][0][0][rs * 72 + soff]     = k0;
        *(bf16x8*)&lds[half][0][0][rs * 72 + soff + 8] = k1;
        *(bf16x8*)&lds[half][1][0][rs * 72 + soff]     = v0;
        *(bf16x8*)&lds[half][1][0][rs * 72 + soff + 8] = v1;
    }
    bf16x8 kr0, kr1, vr0, vr1;
    {
        const __bf16* kp = Kg  + base + (size_t)(kb0 + 64 + rs) * 64 + soff;
        const __bf16* vp = Vtg + base + (size_t)rs * TTOK + kb0 + 64 + soff;
        kr0 = *(const bf16x8*)(kp); kr1 = *(const bf16x8*)(kp + 8);
        vr0 = *(const bf16x8*)(vp); vr1 = *(const bf16x8*)(vp + 8);
    }
    __syncthreads();

    for (int it = 0; it < 16; ++it) {
        const int cur = it & 1;
        const __bf16* Kc = &lds[half][0][cur][0];
        const __bf16* Vc = &lds[half][1][cur][0];

        // ---- S^T = K·Q^T ----
        f32x16 s0, s1;
#pragma unroll
        for (int r = 0; r < 16; ++r) { s0[r] = 0.0f; s1[r] = 0.0f; }
#pragma unroll
        for (int st = 0; st < 4; ++st) {
            bf16x8 a0 = *(const bf16x8*)&Kc[(c32)      * 72 + h32 * 8 + st * 16];
            bf16x8 a1 = *(const bf16x8*)&Kc[(32 + c32) * 72 + h32 * 8 + st * 16];
            s0 = __builtin_amdgcn_mfma_f32_32x32x16_bf16(a0, qf[st], s0, 0, 0, 0);
            s1 = __builtin_amdgcn_mfma_f32_32x32x16_bf16(a1, qf[st], s1, 0, 0, 0);
        }

        // ---- fused per-ks: exp2 -> pack -> half-exchange -> PV ----
#pragma unroll
        for (int ks = 0; ks < 4; ++ks) {
            const f32x16& sv = (ks & 2) ? s1 : s0;
            const int rb = (ks & 1) * 8;
            float p0 = EXP2F(sv[rb + 0]), p1 = EXP2F(sv[rb + 1]);
            float p2 = EXP2F(sv[rb + 2]), p3 = EXP2F(sv[rb + 3]);
            float p4 = EXP2F(sv[rb + 4]), p5 = EXP2F(sv[rb + 5]);
            float p6 = EXP2F(sv[rb + 6]), p7 = EXP2F(sv[rb + 7]);
            lsum += ((p0 + p1) + (p2 + p3)) + ((p4 + p5) + (p6 + p7));
            unsigned A0 = pk2(p0, p1), A1 = pk2(p2, p3);
            unsigned B0 = pk2(p4, p5), B1 = pk2(p6, p7);
            unsigned s0w = h32 ? A0 : B0;
            unsigned s1w = h32 ? A1 : B1;
            unsigned r0 = __shfl_xor(s0w, 32, 64);
            unsigned r1 = __shfl_xor(s1w, 32, 64);
            FU fu;
            fu.u[0] = h32 ? r0 : A0;
            fu.u[1] = h32 ? r1 : A1;
            fu.u[2] = h32 ? B0 : r0;
            fu.u[3] = h32 ? B1 : r1;
            bf16x8 v0 = *(const bf16x8*)&Vc[(c32)      * 72 + h32 * 8 + ks * 16];
            bf16x8 v1 = *(const bf16x8*)&Vc[(32 + c32) * 72 + h32 * 8 + ks * 16];
            O[0] = __builtin_amdgcn_mfma_f32_32x32x16_bf16(v0, fu.v, O[0], 0, 0, 0);
            O[1] = __builtin_amdgcn_mfma_f32_32x32x16_bf16(v1, fu.v, O[1], 0, 0, 0);
        }

        // ---- stage tile it+1 (in regs) -> other buffer ----
        *(bf16x8*)&lds[half][0][cur ^ 1][rs * 72 + soff]     = kr0;
        *(bf16x8*)&lds[half][0][cur ^ 1][rs * 72 + soff + 8] = kr1;
        *(bf16x8*)&lds[half][1][cur ^ 1][rs * 72 + soff]     = vr0;
        *(bf16x8*)&lds[half][1][cur ^ 1][rs * 72 + soff + 8] = vr1;

        // ---- prefetch tile it+2 ----
        {
            int itn = (it + 2) & 15;
            const __bf16* kp = Kg  + base + (size_t)(kb0 + itn * 64 + rs) * 64 + soff;
            const __bf16* vp = Vtg + base + (size_t)rs * TTOK + kb0 + itn * 64 + soff;
            kr0 = *(const bf16x8*)(kp); kr1 = *(const bf16x8*)(kp + 8);
            vr0 = *(const bf16x8*)(vp); vr1 = *(const bf16x8*)(vp + 8);
        }

        // ONE barrier per tile: next-buf writes visible; cur-buf reads done
        __syncthreads();
    }

    // ---- combine halves: waves 4-7 deposit partials, waves 0-3 merge ----
    float* cb = (float*)&lds[0][0][0][0];   // 33 KB < 72 KB, post-barrier safe
    if (wave >= 4) {
        float* me = cb + qw * 2048 + lane * 32;
#pragma unroll
        for (int r = 0; r < 16; ++r) { me[r] = O[0][r]; me[16 + r] = O[1][r]; }
        cb[8192 + qw * 64 + lane] = lsum;
    }
    __syncthreads();
    if (wave >= 4) return;
    {
        const float* pr = cb + qw * 2048 + lane * 32;
#pragma unroll
        for (int r = 0; r < 16; ++r) { O[0][r] += pr[r]; O[1][r] += pr[16 + r]; }
        lsum += cb[8192 + qw * 64 + lane];
    }
    const float ltot = lsum + __shfl_xor(lsum, 32, 64);
    const float inv  = 1.0f / ltot;

    // ---- vq: one-time coalesced global re-read of own-q V column ----
    const int q = q0 + qw * 32 + c32;
    float vq[2][16];
#pragma unroll
    for (int db = 0; db < 2; ++db)
#pragma unroll
        for (int rg = 0; rg < 16; ++rg) {
            int d = db * 32 + (rg & 3) + 8 * (rg >> 2) + 4 * h32;
            vq[db][rg] = (float)Vtg[base + (size_t)d * TTOK + q];
        }

    // ---- epilogue: Y = O/l ; exclusive output mod ; packed bf16 store ----
    const int b = bh >> 4, h = bh & 15;
    float y[2][16];
    float yv = 0.f, v2 = 0.f, yy = 0.f;
#pragma unroll
    for (int db = 0; db < 2; ++db)
#pragma unroll
        for (int rg = 0; rg < 16; ++rg) {
            float yval = O[db][rg] * inv;
            float vval = vq[db][rg];
            y[db][rg] = yval;
            yv += yval * vval; v2 += vval * vval; yy += yval * yval;
        }
    yv += __shfl_xor(yv, 32, 64);
    v2 += __shfl_xor(v2, 32, 64);
    yy += __shfl_xor(yy, 32, 64);
    float scl = (v2 > 0.0f) ? yv / fmaxf(v2, 1.1754943508222875e-38f) : 0.0f;
    float zz = 0.f;
    float zvv[2][16];
#pragma unroll
    for (int db = 0; db < 2; ++db)
#pragma unroll
        for (int rg = 0; rg < 16; ++rg) {
            zvv[db][rg] = y[db][rg] - scl * vq[db][rg];
            zz += zvv[db][rg] * zvv[db][rg];
        }
    zz += __shfl_xor(zz, 32, 64);
    float znorm = sqrtf(zz);
    float refn  = fmaxf(sqrtf(yy), sqrtf(v2));
    bool  wipe  = (v2 > 0.0f) && (znorm <= 1.1920928955078125e-07f * 64.0f * refn);
#pragma unroll
    for (int db = 0; db < 2; ++db)
#pragma unroll
        for (int g = 0; g < 4; ++g) {
            bf16x4 pk;
#pragma unroll
            for (int r = 0; r < 4; ++r)
                pk[r] = (__bf16)(wipe ? 0.0f : zvv[db][4 * g + r]);
            int d = db * 32 + 8 * g + 4 * h32;
            *(bf16x4*)&Zm[((size_t)(b * TTOK + q)) * DM + h * 64 + d] = pk;
        }
}

// =====================================================================
extern "C" void kernel_launch(void* const* d_in, const int* in_sizes, int n_in,
                              void* d_out, int out_size, void* d_ws, size_t ws_size,
                              hipStream_t stream) {
    const float* x  = (const float*)d_in[0];
    const float* Wq = (const float*)d_in[1];
    const float* Wk = (const float*)d_in[2];
    const float* Wv = (const float*)d_in[3];
    const float* Wo = (const float*)d_in[4];

    const size_t NX = (size_t)NTOK * DM;   // 4M
    const size_t NW = (size_t)DM * DM;     // 1M
    __bf16* xb  = (__bf16*)d_ws;
    __bf16* wqb = xb  + NX;
    __bf16* wkb = wqb + NW;
    __bf16* wvb = wkb + NW;
    __bf16* wob = wvb + NW;
    __bf16* Qb  = wob + NW;
    __bf16* Kb  = Qb  + NX;
    __bf16* Vtb = Kb  + NX;
    __bf16* Zmb = Vtb + NX;   // total 24M bf16 = 48 MB

    cvt_all<<<(NX + 4 * NW) / 2048, 256, 0, stream>>>(x, Wq, Wk, Wv, Wo, xb);

    // QKV: z0/z1 = Wq,Wk · x^T ; z2 = x · Wv^T  (LDS-transpose epilogues)
    gemm_qkv<<<dim3(32, 8, 3), 256, 0, stream>>>(
        xb, wqb, wkb, wvb, Qb, Kb, Vtb);

    // attn: 8-wave KV-split blocks (512 thr), 2 blocks/CU = 4 waves/SIMD
    attn_mfma<<<dim3(TTOK / 128, 32), 512, 0, stream>>>(Qb, Kb, Vtb, Zmb);

    // out = Zm · Wo^T (BM=64 x BN=128, 512 blocks, XCD-swizzled)
    gemm_oproj<<<dim3(8, 64), 256, 0, stream>>>(Zmb, wob, (float*)d_out);
}

// Round 7
// 181.100 us; speedup vs baseline: 1.1533x; 1.0191x over previous
//
#include <hip/hip_runtime.h>
#include <math.h>

#define DM   1024
#define TTOK 2048
#define NTOK 4096   // B*T

typedef __bf16 bf16x8 __attribute__((ext_vector_type(8)));
typedef __bf16 bf16x4 __attribute__((ext_vector_type(4)));
typedef __bf16 bf16x2 __attribute__((ext_vector_type(2)));
typedef float  f32x4  __attribute__((ext_vector_type(4)));
typedef float  f32x16 __attribute__((ext_vector_type(16)));

// Q pre-scale: sm_scale (1/8) * log2(e)  -> allows p = exp2(s)
#define QSCALE 0.18033688011112042f

#if defined(__has_builtin)
#if __has_builtin(__builtin_amdgcn_exp2f)
#define EXP2F(x) __builtin_amdgcn_exp2f(x)
#endif
#endif
#ifndef EXP2F
#define EXP2F(x) exp2f(x)
#endif

#define GLDS16(g, l) __builtin_amdgcn_global_load_lds( \
    (__attribute__((address_space(1))) void*)(g),      \
    (__attribute__((address_space(3))) void*)(l), 16, 0, 0)

// pack two f32 -> one dword of 2 bf16 (RNE, same rounding as (__bf16) cast)
__device__ __forceinline__ unsigned pk2(float a, float b) {
    bf16x2 t; t[0] = (__bf16)a; t[1] = (__bf16)b;
    return __builtin_bit_cast(unsigned, t);
}
union FU { unsigned u[4]; bf16x8 v; };

// ---------------- fp32 -> bf16 convert: x + 4 weights in ONE launch ----------------
__global__ __launch_bounds__(256)
void cvt_all(const float* __restrict__ x,  const float* __restrict__ Wq,
             const float* __restrict__ Wk, const float* __restrict__ Wv,
             const float* __restrict__ Wo, __bf16* __restrict__ dst) {
    size_t g = ((size_t)blockIdx.x * 256 + threadIdx.x) * 8;
    const float* s;
    size_t off;
    const size_t NX = (size_t)NTOK * DM;   // 4M
    if (g < NX) { s = x; off = g; }
    else {
        size_t gg = g - NX;
        int w = (int)(gg >> 20);           // 1M-element segments
        off = gg & ((1u << 20) - 1);
        s = (w == 0) ? Wq : (w == 1) ? Wk : (w == 2) ? Wv : Wo;
    }
    float4 a = *(const float4*)(s + off);
    float4 b = *(const float4*)(s + off + 4);
    bf16x8 v;
    v[0] = (__bf16)a.x; v[1] = (__bf16)a.y; v[2] = (__bf16)a.z; v[3] = (__bf16)a.w;
    v[4] = (__bf16)b.x; v[5] = (__bf16)b.y; v[6] = (__bf16)b.z; v[7] = (__bf16)b.w;
    *(bf16x8*)(dst + g) = v;
}

// =====================================================================
// bf16 MFMA GEMM, QKV only (proven R3 structure, untouched).
// C[m,n] = sum_k A[m,k] * B[n,k], 128x128 tile, BK=32.
// Double-buffered LDS staging; next-tile global_load_lds issued BEFORE
// current-tile compute; ONE barrier per K-step. Row-major LDS staging
// (linear global_load_lds dest, 64B-coalesced source).
//   z=0: A=Wq, B=x (m=hd, n=token) -> Q[b,h,t,d] * QSCALE
//   z=1: A=Wk, B=x                  -> K[b,h,t,d]
//   z=2: A=x,  B=Wv (m=token, n=hd) -> Vt[b,h,d,t]
// =====================================================================
#define LSTR 136   // LDS transpose stride (16B-aligned rows, conflict-free)
#define DBUF 8192  // elems per staging buffer (As 4096 + Bs 4096)

__global__ __launch_bounds__(256)
void gemm_qkv(const __bf16* __restrict__ X,
              const __bf16* __restrict__ W0, const __bf16* __restrict__ W1,
              const __bf16* __restrict__ W2,
              __bf16* __restrict__ Oq, __bf16* __restrict__ Ok,
              __bf16* __restrict__ Ovt)
{
    const int z = blockIdx.z;
    const __bf16 *A, *B;
    int m0, n0;
    if (z < 2) {                     // W·x^T : m=hd(1024), n=token(4096)
        A = z ? W1 : W0; B = X;
        m0 = blockIdx.y * 128; n0 = blockIdx.x * 128;
    } else {                         // x·Wv^T : m=token, n=hd
        A = X; B = W2;
        m0 = blockIdx.x * 128; n0 = blockIdx.y * 128;
    }

    // union: double-buffer staging (2 x (As 4K + Bs 4K) = 16K elems)
    //        / 128x136 transpose buffer (17408 elems)
    __shared__ __attribute__((aligned(16))) __bf16 smem[128 * LSTR];

    const int tid  = threadIdx.x;
    const int lane = tid & 63;
    const int wave = tid >> 6;
    const int wm = wave & 1, wn = wave >> 1;
    const int col = lane & 15, quad = lane >> 4;

    const __bf16* Ag = A + (size_t)(m0 + (tid >> 2)) * DM + (tid & 3) * 8;
    const __bf16* Bg = B + (size_t)(n0 + (tid >> 2)) * DM + (tid & 3) * 8;
    __bf16* lA = smem + tid * 8;            // As slot in buffer 0
    __bf16* lB = smem + 4096 + tid * 8;     // Bs slot in buffer 0

    f32x4 acc[4][4];
#pragma unroll
    for (int i = 0; i < 4; ++i)
#pragma unroll
        for (int j = 0; j < 4; ++j)
#pragma unroll
            for (int r = 0; r < 4; ++r) acc[i][j][r] = 0.0f;

    // ---- prologue: stage K-step 0 into buffer 0 ----
    GLDS16(Ag,                   lA);
    GLDS16(Ag + (size_t)64 * DM, lA + 2048);
    GLDS16(Bg,                   lB);
    GLDS16(Bg + (size_t)64 * DM, lB + 2048);
    __syncthreads();   // vmcnt(0) drained by compiler: buf0 ready

    const int nk = DM / 32;   // 32 K-steps
    for (int t = 0; t < nk; ++t) {
        const int cur = (t & 1) * DBUF;
        const int nxt = DBUF - cur;

        // issue next-tile loads FIRST — latency spans the compute below
        if (t + 1 < nk) {
            const int k1 = (t + 1) * 32;
            GLDS16(Ag + k1,                   lA + nxt);
            GLDS16(Ag + (size_t)64 * DM + k1, lA + nxt + 2048);
            GLDS16(Bg + k1,                   lB + nxt);
            GLDS16(Bg + (size_t)64 * DM + k1, lB + nxt + 2048);
        }

        const __bf16* Asr = smem + cur;
        const __bf16* Bsr = smem + cur + 4096;
        bf16x8 af[4], bfr[4];
#pragma unroll
        for (int i = 0; i < 4; ++i)
            af[i] = *(const bf16x8*)&Asr[(wm * 64 + i * 16 + col) * 32 + quad * 8];
#pragma unroll
        for (int j = 0; j < 4; ++j)
            bfr[j] = *(const bf16x8*)&Bsr[(wn * 64 + j * 16 + col) * 32 + quad * 8];
#pragma unroll
        for (int i = 0; i < 4; ++i)
#pragma unroll
            for (int j = 0; j < 4; ++j)
                acc[i][j] = __builtin_amdgcn_mfma_f32_16x16x32_bf16(af[i], bfr[j], acc[i][j], 0, 0, 0);

        __syncthreads();
    }

    // ---- LDS transpose -> packed global stores ----
    const float sc = (z == 0) ? QSCALE : 1.0f;
#pragma unroll
    for (int i = 0; i < 4; ++i)
#pragma unroll
        for (int j = 0; j < 4; ++j) {
            const int ml = wm * 64 + i * 16 + quad * 4;
            const int nl = wn * 64 + j * 16 + col;
            bf16x4 pk;
#pragma unroll
            for (int r = 0; r < 4; ++r) pk[r] = (__bf16)(acc[i][j][r] * sc);
            *(bf16x4*)&smem[nl * LSTR + ml] = pk;   // Ls[n][m]
        }
    __syncthreads();

    // 128 rows x 16 chunks of 8 elems = 2048 chunks; 8 iterations x 256 thr
#pragma unroll
    for (int it = 0; it < 8; ++it) {
        int c   = tid + 256 * it;
        int row = c >> 4;          // n_local
        int ch  = (c & 15) * 8;    // m_local base
        bf16x8 v = *(const bf16x8*)&smem[row * LSTR + ch];
        if (z < 2) {
            // row = token, ch = hd: d-contiguous segments of Q/K[b,h,t,d]
            int t  = n0 + row;
            int b  = t >> 11; t &= 2047;
            int hd = m0 + ch;
            int h  = hd >> 6, d = hd & 63;
            *(bf16x8*)&((z ? Ok : Oq)[(((size_t)(b * 16 + h)) * TTOK + t) * 64 + d]) = v;
        } else {
            // row = hd, ch = token: t-contiguous segments of Vt[b,h,d,t]
            int hd = n0 + row;
            int h  = hd >> 6, d = hd & 63;
            int t  = m0 + ch;
            int b  = t >> 11; t &= 2047;
            *(bf16x8*)&Ovt[(((size_t)(b * 16 + h)) * 64 + d) * TTOK + t] = v;
        }
    }
}

// =====================================================================
// out-proj: out[m][n] = sum_k Zm[m,k]*Wo[n,k], fp32 out.
// BM=64 x BN=128, BK=32 -> grid (8,64) = 512 blocks = 2 blocks/CU.
// Bijective XCD swizzle: XCD c owns m-rows [512c,512c+512).
// (unchanged for attribution)
// =====================================================================
#define ODBUF 6144   // elems per staging buffer (As 2048 + Bs 4096)

__global__ __launch_bounds__(256)
void gemm_oproj(const __bf16* __restrict__ X, const __bf16* __restrict__ Wo,
                float* __restrict__ Of)
{
    const int f = blockIdx.x + 8 * blockIdx.y;   // 0..511 dispatch-linear
    const int c = f & 7, i0 = f >> 3;            // XCD c (round-robin)
    const int m0 = (8 * c + (i0 & 7)) * 64;      // XCD c -> m-rows [512c,512c+512)
    const int n0 = (i0 >> 3) * 128;

    __shared__ __attribute__((aligned(16))) __bf16 smem[2 * ODBUF];

    const int tid  = threadIdx.x;
    const int lane = tid & 63;
    const int wave = tid >> 6;
    const int col = lane & 15, quad = lane >> 4;

    const __bf16* Ag = X  + (size_t)(m0 + (tid >> 2)) * DM + (tid & 3) * 8;  // 64 rows
    const __bf16* Bg = Wo + (size_t)(n0 + (tid >> 2)) * DM + (tid & 3) * 8;  // 128 rows
    __bf16* lA = smem + tid * 8;            // As: [64][32]
    __bf16* lB = smem + 2048 + tid * 8;     // Bs: [128][32]

    f32x4 acc[4][2];
#pragma unroll
    for (int i = 0; i < 4; ++i)
#pragma unroll
        for (int j = 0; j < 2; ++j)
#pragma unroll
            for (int r = 0; r < 4; ++r) acc[i][j][r] = 0.0f;

    GLDS16(Ag,                   lA);
    GLDS16(Bg,                   lB);
    GLDS16(Bg + (size_t)64 * DM, lB + 2048);
    __syncthreads();

    const int nk = DM / 32;
    for (int t = 0; t < nk; ++t) {
        const int cur = (t & 1) * ODBUF;
        const int nxt = ODBUF - cur;
        if (t + 1 < nk) {
            const int k1 = (t + 1) * 32;
            GLDS16(Ag + k1,                   lA + nxt);
            GLDS16(Bg + k1,                   lB + nxt);
            GLDS16(Bg + (size_t)64 * DM + k1, lB + nxt + 2048);
        }
        const __bf16* Asr = smem + cur;
        const __bf16* Bsr = smem + cur + 2048;
        bf16x8 af[4], bfr[2];
#pragma unroll
        for (int i = 0; i < 4; ++i)
            af[i] = *(const bf16x8*)&Asr[(i * 16 + col) * 32 + quad * 8];
#pragma unroll
        for (int j = 0; j < 2; ++j)
            bfr[j] = *(const bf16x8*)&Bsr[(wave * 32 + j * 16 + col) * 32 + quad * 8];
#pragma unroll
        for (int i = 0; i < 4; ++i)
#pragma unroll
            for (int j = 0; j < 2; ++j)
                acc[i][j] = __builtin_amdgcn_mfma_f32_16x16x32_bf16(af[i], bfr[j], acc[i][j], 0, 0, 0);
        __syncthreads();
    }

    // scalar n-fastest fp32 stores: 16 lanes = 64B contiguous
#pragma unroll
    for (int i = 0; i < 4; ++i)
#pragma unroll
        for (int j = 0; j < 2; ++j) {
            const int mb = m0 + i * 16 + quad * 4;
            const int n  = n0 + wave * 32 + j * 16 + col;
#pragma unroll
            for (int r = 0; r < 4; ++r)
                Of[(size_t)(mb + r) * DM + n] = acc[i][j][r];
        }
}

// =====================================================================
// MFMA flash attention v10 = v9 with the spill fixed.
// R6 evidence: launch_bounds(512,4) -> VGPR capped at 64 (CUDA
// min-BLOCKS semantics: 4 blocks/CU = 32 waves/CU) -> ~45 regs spilled
// to scratch every tile (FETCH +6.5MB, muted occupancy gain).
// v10: __launch_bounds__(512, 2) -> 16 waves/CU cap -> VGPR <= 128,
// fits the ~110 live regs, zero spill; LDS 72KB still gives 2 blocks/CU
// = 4 waves/SIMD. Combine buffer relaid [r][lane] (64 consecutive
// floats/row) -> conflict-free (was [lane][r], 1.38M conflicts).
// Waves 0-3: q-sets x keys [0,1024); waves 4-7: same q x [1024,2048);
// exp2-softmax additive => O=O_lo+O_hi, l=l_lo+l_hi via LDS combine.
// In-register P; stride-72 K/V; ONE barrier/tile.
// =====================================================================
__global__ __launch_bounds__(512, 2)
void attn_mfma(const __bf16* __restrict__ Qg, const __bf16* __restrict__ Kg,
               const __bf16* __restrict__ Vtg, __bf16* __restrict__ Zm)
{
    const int bh = blockIdx.y;
    const int q0 = blockIdx.x * 128;
    const size_t base = (size_t)bh * TTOK * 64;

    // [half][kv][buf][64*72]; reused as float combine buffer post-loop
    __shared__ __attribute__((aligned(16))) __bf16 lds[2][2][2][64 * 72];

    const int tid  = threadIdx.x;          // 0..511
    const int lane = tid & 63;
    const int wave = tid >> 6;             // 0..7
    const int half = wave >> 2;            // key range half
    const int qw   = wave & 3;             // q-set
    const int c32  = lane & 31, h32 = lane >> 5;

    // ---- Q frags: direct global -> regs (pre-scaled by QSCALE in GEMM) ----
    bf16x8 qf[4];
    const __bf16* qrow = Qg + base + (size_t)(q0 + qw * 32 + c32) * 64 + h32 * 8;
#pragma unroll
    for (int st = 0; st < 4; ++st)
        qf[st] = *(const bf16x8*)(qrow + st * 16);

    f32x16 O[2];
#pragma unroll
    for (int r = 0; r < 16; ++r) { O[0][r] = 0.0f; O[1][r] = 0.0f; }
    float lsum = 0.0f;

    // staging coords within this half's 256-thread group
    const int tid8 = tid & 255;
    const int rs   = tid8 >> 2;            // 0..63
    const int soff = (tid8 & 3) * 16;
    const int kb0  = half * 1024;          // key base for this half

    // ---- prologue: tile 0 -> buf0 ; tile 1 -> regs ----
    {
        const __bf16* kp = Kg  + base + (size_t)(kb0 + rs) * 64 + soff;
        const __bf16* vp = Vtg + base + (size_t)rs * TTOK + kb0 + soff;
        bf16x8 k0 = *(const bf16x8*)(kp);
        bf16x8 k1 = *(const bf16x8*)(kp + 8);
        bf16x8 v0 = *(const bf16x8*)(vp);
        bf16x8 v1 = *(const bf16x8*)(vp + 8);
        *(bf16x8*)&lds[half][0][0][rs * 72 + soff]     = k0;
        *(bf16x8*)&lds[half][0][0][rs * 72 + soff + 8] = k1;
        *(bf16x8*)&lds[half][1][0][rs * 72 + soff]     = v0;
        *(bf16x8*)&lds[half][1][0][rs * 72 + soff + 8] = v1;
    }
    bf16x8 kr0, kr1, vr0, vr1;
    {
        const __bf16* kp = Kg  + base + (size_t)(kb0 + 64 + rs) * 64 + soff;
        const __bf16* vp = Vtg + base + (size_t)rs * TTOK + kb0 + 64 + soff;
        kr0 = *(const bf16x8*)(kp); kr1 = *(const bf16x8*)(kp + 8);
        vr0 = *(const bf16x8*)(vp); vr1 = *(const bf16x8*)(vp + 8);
    }
    __syncthreads();

    for (int it = 0; it < 16; ++it) {
        const int cur = it & 1;
        const __bf16* Kc = &lds[half][0][cur][0];
        const __bf16* Vc = &lds[half][1][cur][0];

        // ---- S^T = K·Q^T ----
        f32x16 s0, s1;
#pragma unroll
        for (int r = 0; r < 16; ++r) { s0[r] = 0.0f; s1[r] = 0.0f; }
#pragma unroll
        for (int st = 0; st < 4; ++st) {
            bf16x8 a0 = *(const bf16x8*)&Kc[(c32)      * 72 + h32 * 8 + st * 16];
            bf16x8 a1 = *(const bf16x8*)&Kc[(32 + c32) * 72 + h32 * 8 + st * 16];
            s0 = __builtin_amdgcn_mfma_f32_32x32x16_bf16(a0, qf[st], s0, 0, 0, 0);
            s1 = __builtin_amdgcn_mfma_f32_32x32x16_bf16(a1, qf[st], s1, 0, 0, 0);
        }

        // ---- fused per-ks: exp2 -> pack -> half-exchange -> PV ----
#pragma unroll
        for (int ks = 0; ks < 4; ++ks) {
            const f32x16& sv = (ks & 2) ? s1 : s0;
            const int rb = (ks & 1) * 8;
            float p0 = EXP2F(sv[rb + 0]), p1 = EXP2F(sv[rb + 1]);
            float p2 = EXP2F(sv[rb + 2]), p3 = EXP2F(sv[rb + 3]);
            float p4 = EXP2F(sv[rb + 4]), p5 = EXP2F(sv[rb + 5]);
            float p6 = EXP2F(sv[rb + 6]), p7 = EXP2F(sv[rb + 7]);
            lsum += ((p0 + p1) + (p2 + p3)) + ((p4 + p5) + (p6 + p7));
            unsigned A0 = pk2(p0, p1), A1 = pk2(p2, p3);
            unsigned B0 = pk2(p4, p5), B1 = pk2(p6, p7);
            unsigned s0w = h32 ? A0 : B0;
            unsigned s1w = h32 ? A1 : B1;
            unsigned r0 = __shfl_xor(s0w, 32, 64);
            unsigned r1 = __shfl_xor(s1w, 32, 64);
            FU fu;
            fu.u[0] = h32 ? r0 : A0;
            fu.u[1] = h32 ? r1 : A1;
            fu.u[2] = h32 ? B0 : r0;
            fu.u[3] = h32 ? B1 : r1;
            bf16x8 v0 = *(const bf16x8*)&Vc[(c32)      * 72 + h32 * 8 + ks * 16];
            bf16x8 v1 = *(const bf16x8*)&Vc[(32 + c32) * 72 + h32 * 8 + ks * 16];
            O[0] = __builtin_amdgcn_mfma_f32_32x32x16_bf16(v0, fu.v, O[0], 0, 0, 0);
            O[1] = __builtin_amdgcn_mfma_f32_32x32x16_bf16(v1, fu.v, O[1], 0, 0, 0);
        }

        // ---- stage tile it+1 (in regs) -> other buffer ----
        *(bf16x8*)&lds[half][0][cur ^ 1][rs * 72 + soff]     = kr0;
        *(bf16x8*)&lds[half][0][cur ^ 1][rs * 72 + soff + 8] = kr1;
        *(bf16x8*)&lds[half][1][cur ^ 1][rs * 72 + soff]     = vr0;
        *(bf16x8*)&lds[half][1][cur ^ 1][rs * 72 + soff + 8] = vr1;

        // ---- prefetch tile it+2 ----
        {
            int itn = (it + 2) & 15;
            const __bf16* kp = Kg  + base + (size_t)(kb0 + itn * 64 + rs) * 64 + soff;
            const __bf16* vp = Vtg + base + (size_t)rs * TTOK + kb0 + itn * 64 + soff;
            kr0 = *(const bf16x8*)(kp); kr1 = *(const bf16x8*)(kp + 8);
            vr0 = *(const bf16x8*)(vp); vr1 = *(const bf16x8*)(vp + 8);
        }

        // ONE barrier per tile: next-buf writes visible; cur-buf reads done
        __syncthreads();
    }

    // ---- combine halves: waves 4-7 deposit partials, waves 0-3 merge ----
    // layout [qw][r][lane]: 64 consecutive floats per row -> conflict-free
    float* cb = (float*)&lds[0][0][0][0];   // 33 KB < 72 KB, post-barrier safe
    if (wave >= 4) {
        float* me = cb + qw * 2048;
#pragma unroll
        for (int r = 0; r < 16; ++r) {
            me[r * 64 + lane]        = O[0][r];
            me[(16 + r) * 64 + lane] = O[1][r];
        }
        cb[8192 + qw * 64 + lane] = lsum;
    }
    __syncthreads();
    if (wave >= 4) return;
    {
        const float* pr = cb + qw * 2048;
#pragma unroll
        for (int r = 0; r < 16; ++r) {
            O[0][r] += pr[r * 64 + lane];
            O[1][r] += pr[(16 + r) * 64 + lane];
        }
        lsum += cb[8192 + qw * 64 + lane];
    }
    const float ltot = lsum + __shfl_xor(lsum, 32, 64);
    const float inv  = 1.0f / ltot;

    // ---- vq: one-time coalesced global re-read of own-q V column ----
    const int q = q0 + qw * 32 + c32;
    float vq[2][16];
#pragma unroll
    for (int db = 0; db < 2; ++db)
#pragma unroll
        for (int rg = 0; rg < 16; ++rg) {
            int d = db * 32 + (rg & 3) + 8 * (rg >> 2) + 4 * h32;
            vq[db][rg] = (float)Vtg[base + (size_t)d * TTOK + q];
        }

    // ---- epilogue: Y = O/l ; exclusive output mod ; packed bf16 store ----
    const int b = bh >> 4, h = bh & 15;
    float y[2][16];
    float yv = 0.f, v2 = 0.f, yy = 0.f;
#pragma unroll
    for (int db = 0; db < 2; ++db)
#pragma unroll
        for (int rg = 0; rg < 16; ++rg) {
            float yval = O[db][rg] * inv;
            float vval = vq[db][rg];
            y[db][rg] = yval;
            yv += yval * vval; v2 += vval * vval; yy += yval * yval;
        }
    yv += __shfl_xor(yv, 32, 64);
    v2 += __shfl_xor(v2, 32, 64);
    yy += __shfl_xor(yy, 32, 64);
    float scl = (v2 > 0.0f) ? yv / fmaxf(v2, 1.1754943508222875e-38f) : 0.0f;
    float zz = 0.f;
    float zvv[2][16];
#pragma unroll
    for (int db = 0; db < 2; ++db)
#pragma unroll
        for (int rg = 0; rg < 16; ++rg) {
            zvv[db][rg] = y[db][rg] - scl * vq[db][rg];
            zz += zvv[db][rg] * zvv[db][rg];
        }
    zz += __shfl_xor(zz, 32, 64);
    float znorm = sqrtf(zz);
    float refn  = fmaxf(sqrtf(yy), sqrtf(v2));
    bool  wipe  = (v2 > 0.0f) && (znorm <= 1.1920928955078125e-07f * 64.0f * refn);
#pragma unroll
    for (int db = 0; db < 2; ++db)
#pragma unroll
        for (int g = 0; g < 4; ++g) {
            bf16x4 pk;
#pragma unroll
            for (int r = 0; r < 4; ++r)
                pk[r] = (__bf16)(wipe ? 0.0f : zvv[db][4 * g + r]);
            int d = db * 32 + 8 * g + 4 * h32;
            *(bf16x4*)&Zm[((size_t)(b * TTOK + q)) * DM + h * 64 + d] = pk;
        }
}

// =====================================================================
extern "C" void kernel_launch(void* const* d_in, const int* in_sizes, int n_in,
                              void* d_out, int out_size, void* d_ws, size_t ws_size,
                              hipStream_t stream) {
    const float* x  = (const float*)d_in[0];
    const float* Wq = (const float*)d_in[1];
    const float* Wk = (const float*)d_in[2];
    const float* Wv = (const float*)d_in[3];
    const float* Wo = (const float*)d_in[4];

    const size_t NX = (size_t)NTOK * DM;   // 4M
    const size_t NW = (size_t)DM * DM;     // 1M
    __bf16* xb  = (__bf16*)d_ws;
    __bf16* wqb = xb  + NX;
    __bf16* wkb = wqb + NW;
    __bf16* wvb = wkb + NW;
    __bf16* wob = wvb + NW;
    __bf16* Qb  = wob + NW;
    __bf16* Kb  = Qb  + NX;
    __bf16* Vtb = Kb  + NX;
    __bf16* Zmb = Vtb + NX;   // total 24M bf16 = 48 MB

    cvt_all<<<(NX + 4 * NW) / 2048, 256, 0, stream>>>(x, Wq, Wk, Wv, Wo, xb);

    // QKV: z0/z1 = Wq,Wk · x^T ; z2 = x · Wv^T  (LDS-transpose epilogues)
    gemm_qkv<<<dim3(32, 8, 3), 256, 0, stream>>>(
        xb, wqb, wkb, wvb, Qb, Kb, Vtb);

    // attn: 8-wave KV-split blocks (512 thr), 2 blocks/CU = 4 waves/SIMD
    attn_mfma<<<dim3(TTOK / 128, 32), 512, 0, stream>>>(Qb, Kb, Vtb, Zmb);

    // out = Zm · Wo^T (BM=64 x BN=128, 512 blocks, XCD-swizzled)
    gemm_oproj<<<dim3(8, 64), 256, 0, stream>>>(Zmb, wob, (float*)d_out);
}